// Round 3
// baseline (832.607 us; speedup 1.0000x reference)
//
#include <hip/hip_runtime.h>
#include <stdint.h>

#define F_IN 512
#define F_OUT 16
#define BSHIFT 5
#define BN 32   // nodes per bucket

// ---------------- P1: bucket histogram over dst ----------------
__global__ void k_bhist(const int* __restrict__ ei, int E, int* __restrict__ bcnt) {
    int i = blockIdx.x * blockDim.x + threadIdx.x;
    int stride = gridDim.x * blockDim.x;
    for (int e = i; e < E; e += stride) {
        int d = ei[(size_t)E + e];
        atomicAdd(&bcnt[d >> BSHIFT], 1);
    }
}

// ---------------- P2: exclusive scan of bucket counts (single block, K<=4096) ----------------
__global__ __launch_bounds__(1024) void k_bscan(const int* __restrict__ bcnt, int K,
                                                int* __restrict__ bbase, int* __restrict__ bcur) {
    __shared__ int sm[1024];
    int t = threadIdx.x;
    int v[4];
    int s = 0;
#pragma unroll
    for (int i = 0; i < 4; i++) {
        int idx = t * 4 + i;
        v[i] = (idx < K) ? bcnt[idx] : 0;
        s += v[i];
    }
    sm[t] = s;
    __syncthreads();
    for (int off = 1; off < 1024; off <<= 1) {
        int add = (t >= off) ? sm[t - off] : 0;
        __syncthreads();
        sm[t] += add;
        __syncthreads();
    }
    int run = sm[t] - s;  // exclusive prefix of this thread's 4-chunk
#pragma unroll
    for (int i = 0; i < 4; i++) {
        int idx = t * 4 + i;
        if (idx < K) { bbase[idx] = run; bcur[idx] = run; }
        run += v[i];
    }
}

// ---------------- P3: partition edges into buckets (packed src|dst_lo) ----------------
// Bucket cursors fill sequentially in time -> each 64B line of part[] written once.
__global__ void k_part(const int* __restrict__ ei, int E, int* __restrict__ bcur,
                       unsigned* __restrict__ part) {
    int i = blockIdx.x * blockDim.x + threadIdx.x;
    int stride = gridDim.x * blockDim.x;
    for (int e = i; e < E; e += stride) {
        int s = ei[e];
        int d = ei[(size_t)E + e];
        int pos = atomicAdd(&bcur[d >> BSHIFT], 1);
        part[pos] = ((unsigned)s << BSHIFT) | (unsigned)(d & (BN - 1));
    }
}

// ---------------- P4: per-bucket: node hist + dinv + offsets + CSR placement ----------------
__global__ __launch_bounds__(256) void k_prep(const unsigned* __restrict__ part,
                                              const int* __restrict__ bbase, const int* __restrict__ bcnt,
                                              int* __restrict__ hist, float* __restrict__ dinv,
                                              int* __restrict__ offsets, int* __restrict__ csr, int N) {
    __shared__ int ncnt[BN], sc[BN], cur[BN];
    int k = blockIdx.x;
    int t = threadIdx.x;
    int base = bbase[k], cnt = bcnt[k];
    int d0 = k << BSHIFT;
    if (t < BN) ncnt[t] = 0;
    __syncthreads();
    for (int i = t; i < cnt; i += 256)
        atomicAdd(&ncnt[part[base + i] & (BN - 1)], 1);
    __syncthreads();
    if (t < BN) {  // 32-lane shfl inclusive scan -> exclusive
        int v = ncnt[t];
        for (int off = 1; off < BN; off <<= 1) {
            int u = __shfl_up(v, off);
            if (t >= off) v += u;
        }
        sc[t] = v - ncnt[t];
    }
    __syncthreads();
    if (t < BN) {
        int n = d0 + t;
        if (n < N) {
            int off = base + sc[t];
            offsets[n] = off;
            cur[t] = off;
            hist[n] = ncnt[t];
            dinv[n] = rsqrtf((float)(ncnt[t] + 1));
        }
    }
    __syncthreads();
    for (int i = t; i < cnt; i += 256) {
        unsigned p = part[base + i];
        int pos = atomicAdd(&cur[p & (BN - 1)], 1);
        csr[pos] = (int)(p >> BSHIFT);
    }
}

// ---------------- K5: xw1' = dinv[n] * (x @ W1) ----------------
__global__ __launch_bounds__(256) void k_gemm1(const float* __restrict__ x, const float* __restrict__ W1,
                                               const float* __restrict__ dinv, float* __restrict__ xw1p, int N) {
    __shared__ float Wt[16 * 516];
    for (int idx = threadIdx.x; idx < F_IN * F_OUT; idx += 256) {
        int k = idx >> 4, j = idx & 15;
        Wt[j * 516 + k] = W1[idx];
    }
    __syncthreads();

    int lane = threadIdx.x & 63;
    int wave = threadIdx.x >> 6;
    int grp  = lane >> 4;
    int j    = lane & 15;
    int node = blockIdx.x * 16 + wave * 4 + grp;
    if (node >= N) return;

    const float4* xr = (const float4*)(x + (size_t)node * F_IN);
    const float4* wr = (const float4*)(Wt + j * 516);
    float acc = 0.0f;
#pragma unroll 4
    for (int kk = 0; kk < F_IN / 4; kk++) {
        float4 xv = xr[kk];
        float4 wv = wr[kk];
        acc += xv.x * wv.x + xv.y * wv.y + xv.z * wv.z + xv.w * wv.w;
    }
    xw1p[(size_t)node * F_OUT + j] = dinv[node] * acc;
}

// ---------------- K6: agg1 + bias + ReLU + fused (h @ W2) * dinv ----------------
__global__ __launch_bounds__(256) void k_agg1(const float* __restrict__ xw, const int* __restrict__ offsets,
                                              const int* __restrict__ hist, const float* __restrict__ dinv,
                                              const int* __restrict__ csr, const float* __restrict__ b1,
                                              const float* __restrict__ W2, float* __restrict__ xw2p, int N) {
    __shared__ float W2s[256];
    if (threadIdx.x < 256) W2s[threadIdx.x] = W2[threadIdx.x];
    __syncthreads();

    int lane = threadIdx.x & 63;
    int wave = threadIdx.x >> 6;
    int grp  = lane >> 4;
    int j    = lane & 15;
    int node = blockIdx.x * 16 + wave * 4 + grp;
    if (node >= N) return;

    float dn = dinv[node];
    float acc = xw[(size_t)node * F_OUT + j];
    float acc2 = 0.0f;
    int start = offsets[node], cnt = hist[node];
    int i = 0;
    for (; i + 2 <= cnt; i += 2) {
        int s0 = csr[start + i];
        int s1 = csr[start + i + 1];
        acc  += xw[(size_t)s0 * F_OUT + j];
        acc2 += xw[(size_t)s1 * F_OUT + j];
    }
    if (i < cnt) acc += xw[(size_t)csr[start + i] * F_OUT + j];

    float h = fmaxf(dn * (acc + acc2) + b1[j], 0.0f);

    float o = 0.0f;
    int base = lane & 48;
#pragma unroll
    for (int r = 0; r < 16; r++) {
        float hr = __shfl(h, base + r);
        o += hr * W2s[r * 16 + j];
    }
    xw2p[(size_t)node * F_OUT + j] = dn * o;
}

// ---------------- K7: agg2 + bias + ReLU + fused mean-pool partials ----------------
__global__ __launch_bounds__(256) void k_agg2(const float* __restrict__ xw, const int* __restrict__ offsets,
                                              const int* __restrict__ hist, const float* __restrict__ dinv,
                                              const int* __restrict__ csr, const float* __restrict__ b2,
                                              float* __restrict__ partials, int N) {
    int lane = threadIdx.x & 63;
    int wave = threadIdx.x >> 6;
    int grp  = lane >> 4;
    int j    = lane & 15;
    int node = blockIdx.x * 16 + wave * 4 + grp;

    float r = 0.0f;
    if (node < N) {
        float dn = dinv[node];
        float acc = xw[(size_t)node * F_OUT + j];
        float acc2 = 0.0f;
        int start = offsets[node], cnt = hist[node];
        int i = 0;
        for (; i + 2 <= cnt; i += 2) {
            int s0 = csr[start + i];
            int s1 = csr[start + i + 1];
            acc  += xw[(size_t)s0 * F_OUT + j];
            acc2 += xw[(size_t)s1 * F_OUT + j];
        }
        if (i < cnt) acc += xw[(size_t)csr[start + i] * F_OUT + j];
        r = fmaxf(dn * (acc + acc2) + b2[j], 0.0f);
    }
    r += __shfl_xor(r, 16);
    r += __shfl_xor(r, 32);
    __shared__ float sm[4][16];
    if (lane < 16) sm[wave][j] = r;
    __syncthreads();
    if (threadIdx.x < 16) {
        float s = sm[0][threadIdx.x] + sm[1][threadIdx.x] + sm[2][threadIdx.x] + sm[3][threadIdx.x];
        partials[(size_t)blockIdx.x * 16 + threadIdx.x] = s;
    }
}

// ---------------- K8: final reduce + fc ----------------
__global__ void k_final(const float* __restrict__ partials, int NB, const float* __restrict__ fc_w,
                        const float* __restrict__ fc_b, float* __restrict__ out, float invN) {
    __shared__ float sm[64][16];
    int t = threadIdx.x;  // 1024 threads
    int g = t >> 4, j = t & 15;
    float s = 0.0f;
    for (int bk = g; bk < NB; bk += 64) s += partials[(size_t)bk * 16 + j];
    sm[g][j] = s;
    __syncthreads();
    for (int str = 32; str > 0; str >>= 1) {
        if (g < str) sm[g][j] += sm[g + str][j];
        __syncthreads();
    }
    if (t == 0) {
        float acc = fc_b[0];
#pragma unroll
        for (int jj = 0; jj < 16; jj++) acc += sm[0][jj] * invN * fc_w[jj];
        out[0] = acc;
    }
}

extern "C" void kernel_launch(void* const* d_in, const int* in_sizes, int n_in,
                              void* d_out, int out_size, void* d_ws, size_t ws_size,
                              hipStream_t stream) {
    const float* x   = (const float*)d_in[0];
    const int*   ei  = (const int*)d_in[1];
    const float* W1  = (const float*)d_in[2];
    const float* b1  = (const float*)d_in[3];
    const float* W2  = (const float*)d_in[4];
    const float* b2  = (const float*)d_in[5];
    const float* fcw = (const float*)d_in[6];
    const float* fcb = (const float*)d_in[7];
    float* out = (float*)d_out;

    int N = in_sizes[0] / F_IN;   // 100000
    int E = in_sizes[1] / 2;      // 3200000
    int K = (N + BN - 1) >> BSHIFT;  // 3125 buckets

    // ---- workspace carve-up (256B aligned); xw1p/xw2p alias part (consumed by k_prep) ----
    char* p = (char*)d_ws;
    auto alloc = [&](size_t bytes) {
        void* r = (void*)p;
        p += (bytes + 255) & ~(size_t)255;
        return r;
    };
    int*   bcnt    = (int*)alloc((size_t)K * 4);
    int*   bbase   = (int*)alloc((size_t)K * 4);
    int*   bcur    = (int*)alloc((size_t)K * 4);
    int*   hist    = (int*)alloc((size_t)N * 4);
    int*   offsets = (int*)alloc((size_t)N * 4);
    float* dinv    = (float*)alloc((size_t)N * 4);
    int*   csr     = (int*)alloc((size_t)E * 4);
    unsigned* part = (unsigned*)alloc((size_t)E * 4);   // 12.8 MB
    int NB_NODE = (N + 15) / 16;                        // 6250
    float* partials = (float*)alloc((size_t)NB_NODE * 16 * 4);
    // alias: part region reused for xw after k_prep (2*N*16*4 = 12.8 MB == E*4)
    float* xw1p = (float*)part;
    float* xw2p = xw1p + (size_t)N * F_OUT;

    hipMemsetAsync(bcnt, 0, (size_t)K * 4, stream);

    k_bhist<<<2048, 256, 0, stream>>>(ei, E, bcnt);
    k_bscan<<<1, 1024, 0, stream>>>(bcnt, K, bbase, bcur);
    k_part<<<2048, 256, 0, stream>>>(ei, E, bcur, part);
    k_prep<<<K, 256, 0, stream>>>(part, bbase, bcnt, hist, dinv, offsets, csr, N);

    k_gemm1<<<NB_NODE, 256, 0, stream>>>(x, W1, dinv, xw1p, N);
    k_agg1<<<NB_NODE, 256, 0, stream>>>(xw1p, offsets, hist, dinv, csr, b1, W2, xw2p, N);
    k_agg2<<<NB_NODE, 256, 0, stream>>>(xw2p, offsets, hist, dinv, csr, b2, partials, N);
    k_final<<<1, 1024, 0, stream>>>(partials, NB_NODE, fcw, fcb, out, 1.0f / (float)N);
}

// Round 4
// 438.340 us; speedup vs baseline: 1.8995x; 1.8995x over previous
//
#include <hip/hip_runtime.h>
#include <stdint.h>

#define F_IN 512
#define F_OUT 16
#define CB_SHIFT 8
#define CB_W 256          // nodes per coarse bucket
#define PER 12500         // edges per partition block

// ---------------- P1: per-block LDS histogram over coarse buckets ----------------
__global__ __launch_bounds__(256) void k_chist(const int* __restrict__ ei, int E, int K1,
                                               int* __restrict__ cnt) {
    __shared__ int h[512];
    int t = threadIdx.x;
    for (int i = t; i < K1; i += 256) h[i] = 0;
    __syncthreads();
    int e0 = blockIdx.x * PER, e1 = min(E, e0 + PER);
    for (int e = e0 + t; e < e1; e += 256)
        atomicAdd(&h[ei[(size_t)E + e] >> CB_SHIFT], 1);
    __syncthreads();
    for (int i = t; i < K1; i += 256) cnt[blockIdx.x * K1 + i] = h[i];
}

// ---------------- P2: column scan -> per-(block,bucket) bases (single block) ----------------
__global__ __launch_bounds__(512) void k_cscan(const int* __restrict__ cnt, int B, int K1,
                                               int* __restrict__ base, int* __restrict__ bucketBase,
                                               int* __restrict__ bucketCnt) {
    __shared__ int sm[512];
    int k = threadIdx.x;
    int tot = 0;
    if (k < K1)
        for (int b = 0; b < B; b++) tot += cnt[b * K1 + k];   // row-coalesced across threads
    sm[k] = tot;
    __syncthreads();
    for (int off = 1; off < 512; off <<= 1) {
        int add = (k >= off) ? sm[k - off] : 0;
        __syncthreads();
        sm[k] += add;
        __syncthreads();
    }
    int excl = sm[k] - tot;
    if (k < K1) {
        bucketBase[k] = excl;
        bucketCnt[k] = tot;
        int run = excl;
        for (int b = 0; b < B; b++) {
            base[b * K1 + k] = run;        // row-coalesced
            run += cnt[b * K1 + k];
        }
    }
}

// ---------------- P3: per-block LDS counting sort, line-complete streaming output ----------------
__global__ __launch_bounds__(512) void k_csort(const int* __restrict__ ei, int E, int K1,
                                               const int* __restrict__ base, unsigned* __restrict__ part) {
    __shared__ unsigned sorted[12544];
    __shared__ int h[512], lb[512], cur[512], gb[512];
    int t = threadIdx.x;
    int e0 = blockIdx.x * PER, e1 = min(E, e0 + PER);
    int C = e1 - e0;
    h[t] = 0;
    __syncthreads();
    for (int e = e0 + t; e < e1; e += 512)
        atomicAdd(&h[ei[(size_t)E + e] >> CB_SHIFT], 1);
    __syncthreads();
    int v = h[t];
    lb[t] = v;
    __syncthreads();
    for (int off = 1; off < 512; off <<= 1) {
        int add = (t >= off) ? lb[t - off] : 0;
        __syncthreads();
        lb[t] += add;
        __syncthreads();
    }
    int excl = lb[t] - v;
    __syncthreads();
    lb[t] = excl;
    cur[t] = excl;
    if (t < K1) gb[t] = base[blockIdx.x * K1 + t];
    __syncthreads();
    for (int e = e0 + t; e < e1; e += 512) {
        int s = ei[e];
        int d = ei[(size_t)E + e];
        int pos = atomicAdd(&cur[d >> CB_SHIFT], 1);           // LDS atomic
        sorted[pos] = ((unsigned)s << CB_SHIFT) | (unsigned)(d & (CB_W - 1));
    }
    __syncthreads();
    // stream out in position order: consecutive i -> consecutive global addresses per bucket run
    for (int i = t; i < C; i += 512) {
        int lo = 0, hi = K1 - 1;
        while (lo < hi) {                                       // last k with lb[k] <= i
            int mid = (lo + hi + 1) >> 1;
            if (lb[mid] <= i) lo = mid; else hi = mid - 1;
        }
        part[(size_t)gb[lo] + (i - lb[lo])] = sorted[i];
    }
}

// ---------------- P4: per coarse bucket: node hist/dinv/offsets + CSR ----------------
__global__ __launch_bounds__(256) void k_prep2(const unsigned* __restrict__ part,
                                               const int* __restrict__ bucketBase, const int* __restrict__ bucketCnt,
                                               int* __restrict__ hist, float* __restrict__ dinv,
                                               int* __restrict__ offsets, int* __restrict__ csr, int N) {
    __shared__ int fh[CB_W], fb[CB_W], cur[CB_W];
    int k = blockIdx.x, t = threadIdx.x;
    int base = bucketBase[k], cnt = bucketCnt[k];
    int d0 = k << CB_SHIFT;
    fh[t] = 0;
    __syncthreads();
    for (int i = t; i < cnt; i += 256)
        atomicAdd(&fh[part[(size_t)base + i] & (CB_W - 1)], 1);  // LDS atomic
    __syncthreads();
    int v = fh[t];
    fb[t] = v;
    __syncthreads();
    for (int off = 1; off < 256; off <<= 1) {
        int add = (t >= off) ? fb[t - off] : 0;
        __syncthreads();
        fb[t] += add;
        __syncthreads();
    }
    int excl = fb[t] - v;
    int n = d0 + t;
    if (n < N) {
        offsets[n] = base + excl;
        hist[n] = v;
        dinv[n] = rsqrtf((float)(v + 1));
    }
    cur[t] = excl;
    __syncthreads();
    for (int i = t; i < cnt; i += 256) {
        unsigned e = part[(size_t)base + i];
        int pos = atomicAdd(&cur[e & (CB_W - 1)], 1);
        csr[(size_t)base + pos] = (int)(e >> CB_SHIFT);          // 4B scatter inside 33KB 1-block window
    }
}

// ---------------- K5: xw1' = dinv[n] * (x @ W1) ----------------
__global__ __launch_bounds__(256) void k_gemm1(const float* __restrict__ x, const float* __restrict__ W1,
                                               const float* __restrict__ dinv, float* __restrict__ xw1p, int N) {
    __shared__ float Wt[16 * 516];
    for (int idx = threadIdx.x; idx < F_IN * F_OUT; idx += 256) {
        int k = idx >> 4, j = idx & 15;
        Wt[j * 516 + k] = W1[idx];
    }
    __syncthreads();

    int lane = threadIdx.x & 63;
    int wave = threadIdx.x >> 6;
    int grp  = lane >> 4;
    int j    = lane & 15;
    int node = blockIdx.x * 16 + wave * 4 + grp;
    if (node >= N) return;

    const float4* xr = (const float4*)(x + (size_t)node * F_IN);
    const float4* wr = (const float4*)(Wt + j * 516);
    float acc = 0.0f;
#pragma unroll 4
    for (int kk = 0; kk < F_IN / 4; kk++) {
        float4 xv = xr[kk];
        float4 wv = wr[kk];
        acc += xv.x * wv.x + xv.y * wv.y + xv.z * wv.z + xv.w * wv.w;
    }
    xw1p[(size_t)node * F_OUT + j] = dinv[node] * acc;
}

// ---------------- K6: agg1 + bias + ReLU + fused (h @ W2) * dinv ----------------
__global__ __launch_bounds__(256) void k_agg1(const float* __restrict__ xw, const int* __restrict__ offsets,
                                              const int* __restrict__ hist, const float* __restrict__ dinv,
                                              const int* __restrict__ csr, const float* __restrict__ b1,
                                              const float* __restrict__ W2, float* __restrict__ xw2p, int N) {
    __shared__ float W2s[256];
    if (threadIdx.x < 256) W2s[threadIdx.x] = W2[threadIdx.x];
    __syncthreads();

    int lane = threadIdx.x & 63;
    int wave = threadIdx.x >> 6;
    int grp  = lane >> 4;
    int j    = lane & 15;
    int node = blockIdx.x * 16 + wave * 4 + grp;
    if (node >= N) return;

    float dn = dinv[node];
    float acc = xw[(size_t)node * F_OUT + j];
    float acc2 = 0.0f;
    int start = offsets[node], cnt = hist[node];
    int i = 0;
    for (; i + 2 <= cnt; i += 2) {
        int s0 = csr[start + i];
        int s1 = csr[start + i + 1];
        acc  += xw[(size_t)s0 * F_OUT + j];
        acc2 += xw[(size_t)s1 * F_OUT + j];
    }
    if (i < cnt) acc += xw[(size_t)csr[start + i] * F_OUT + j];

    float h = fmaxf(dn * (acc + acc2) + b1[j], 0.0f);

    float o = 0.0f;
    int base = lane & 48;
#pragma unroll
    for (int r = 0; r < 16; r++) {
        float hr = __shfl(h, base + r);
        o += hr * W2s[r * 16 + j];
    }
    xw2p[(size_t)node * F_OUT + j] = dn * o;
}

// ---------------- K7: agg2 + bias + ReLU + fused mean-pool partials ----------------
__global__ __launch_bounds__(256) void k_agg2(const float* __restrict__ xw, const int* __restrict__ offsets,
                                              const int* __restrict__ hist, const float* __restrict__ dinv,
                                              const int* __restrict__ csr, const float* __restrict__ b2,
                                              float* __restrict__ partials, int N) {
    int lane = threadIdx.x & 63;
    int wave = threadIdx.x >> 6;
    int grp  = lane >> 4;
    int j    = lane & 15;
    int node = blockIdx.x * 16 + wave * 4 + grp;

    float r = 0.0f;
    if (node < N) {
        float dn = dinv[node];
        float acc = xw[(size_t)node * F_OUT + j];
        float acc2 = 0.0f;
        int start = offsets[node], cnt = hist[node];
        int i = 0;
        for (; i + 2 <= cnt; i += 2) {
            int s0 = csr[start + i];
            int s1 = csr[start + i + 1];
            acc  += xw[(size_t)s0 * F_OUT + j];
            acc2 += xw[(size_t)s1 * F_OUT + j];
        }
        if (i < cnt) acc += xw[(size_t)csr[start + i] * F_OUT + j];
        r = fmaxf(dn * (acc + acc2) + b2[j], 0.0f);
    }
    r += __shfl_xor(r, 16);
    r += __shfl_xor(r, 32);
    __shared__ float sm[4][16];
    if (lane < 16) sm[wave][j] = r;
    __syncthreads();
    if (threadIdx.x < 16) {
        float s = sm[0][threadIdx.x] + sm[1][threadIdx.x] + sm[2][threadIdx.x] + sm[3][threadIdx.x];
        partials[(size_t)blockIdx.x * 16 + threadIdx.x] = s;
    }
}

// ---------------- K8: final reduce + fc ----------------
__global__ void k_final(const float* __restrict__ partials, int NB, const float* __restrict__ fc_w,
                        const float* __restrict__ fc_b, float* __restrict__ out, float invN) {
    __shared__ float sm[64][16];
    int t = threadIdx.x;  // 1024 threads
    int g = t >> 4, j = t & 15;
    float s = 0.0f;
    for (int bk = g; bk < NB; bk += 64) s += partials[(size_t)bk * 16 + j];
    sm[g][j] = s;
    __syncthreads();
    for (int str = 32; str > 0; str >>= 1) {
        if (g < str) sm[g][j] += sm[g + str][j];
        __syncthreads();
    }
    if (t == 0) {
        float acc = fc_b[0];
#pragma unroll
        for (int jj = 0; jj < 16; jj++) acc += sm[0][jj] * invN * fc_w[jj];
        out[0] = acc;
    }
}

extern "C" void kernel_launch(void* const* d_in, const int* in_sizes, int n_in,
                              void* d_out, int out_size, void* d_ws, size_t ws_size,
                              hipStream_t stream) {
    const float* x   = (const float*)d_in[0];
    const int*   ei  = (const int*)d_in[1];
    const float* W1  = (const float*)d_in[2];
    const float* b1  = (const float*)d_in[3];
    const float* W2  = (const float*)d_in[4];
    const float* b2  = (const float*)d_in[5];
    const float* fcw = (const float*)d_in[6];
    const float* fcb = (const float*)d_in[7];
    float* out = (float*)d_out;

    int N = in_sizes[0] / F_IN;            // 100000
    int E = in_sizes[1] / 2;               // 3200000
    int K1 = (N + CB_W - 1) >> CB_SHIFT;   // 391 coarse buckets
    int B1 = (E + PER - 1) / PER;          // 256 partition blocks

    // ---- workspace carve-up (256B aligned) ----
    char* p = (char*)d_ws;
    auto alloc = [&](size_t bytes) {
        void* r = (void*)p;
        p += (bytes + 255) & ~(size_t)255;
        return r;
    };
    int*   cnt        = (int*)alloc((size_t)B1 * K1 * 4);
    int*   base       = (int*)alloc((size_t)B1 * K1 * 4);
    int*   bucketBase = (int*)alloc((size_t)K1 * 4);
    int*   bucketCnt  = (int*)alloc((size_t)K1 * 4);
    int*   hist       = (int*)alloc((size_t)N * 4);
    int*   offsets    = (int*)alloc((size_t)N * 4);
    float* dinv       = (float*)alloc((size_t)N * 4);
    int*   csr        = (int*)alloc((size_t)E * 4);
    unsigned* part    = (unsigned*)alloc((size_t)E * 4);    // 12.8 MB
    int NB_NODE = (N + 15) / 16;                            // 6250
    float* partials = (float*)alloc((size_t)NB_NODE * 16 * 4);
    // alias: part region reused for xw after k_prep2 (2*N*16*4 == E*4)
    float* xw1p = (float*)part;
    float* xw2p = xw1p + (size_t)N * F_OUT;

    k_chist<<<B1, 256, 0, stream>>>(ei, E, K1, cnt);
    k_cscan<<<1, 512, 0, stream>>>(cnt, B1, K1, base, bucketBase, bucketCnt);
    k_csort<<<B1, 512, 0, stream>>>(ei, E, K1, base, part);
    k_prep2<<<K1, 256, 0, stream>>>(part, bucketBase, bucketCnt, hist, dinv, offsets, csr, N);

    k_gemm1<<<NB_NODE, 256, 0, stream>>>(x, W1, dinv, xw1p, N);
    k_agg1<<<NB_NODE, 256, 0, stream>>>(xw1p, offsets, hist, dinv, csr, b1, W2, xw2p, N);
    k_agg2<<<NB_NODE, 256, 0, stream>>>(xw2p, offsets, hist, dinv, csr, b2, partials, N);
    k_final<<<1, 1024, 0, stream>>>(partials, NB_NODE, fcw, fcb, out, 1.0f / (float)N);
}

// Round 5
// 417.624 us; speedup vs baseline: 1.9937x; 1.0496x over previous
//
#include <hip/hip_runtime.h>
#include <stdint.h>

#define F_IN 512
#define F_OUT 16
#define CB_SHIFT 8
#define CB_W 256          // nodes per coarse bucket
#define PER 12500         // edges per partition block

// ---------------- P1: per-block LDS histogram over coarse buckets ----------------
__global__ __launch_bounds__(256) void k_chist(const int* __restrict__ ei, int E, int K1,
                                               int* __restrict__ cnt) {
    __shared__ int h[512];
    int t = threadIdx.x;
    for (int i = t; i < K1; i += 256) h[i] = 0;
    __syncthreads();
    int e0 = blockIdx.x * PER, e1 = min(E, e0 + PER);
    for (int e = e0 + t; e < e1; e += 256)
        atomicAdd(&h[ei[(size_t)E + e] >> CB_SHIFT], 1);
    __syncthreads();
    for (int i = t; i < K1; i += 256) cnt[blockIdx.x * K1 + i] = h[i];
}

// ---------------- P2: column scan -> per-(block,bucket) bases (single block) ----------------
__global__ __launch_bounds__(512) void k_cscan(const int* __restrict__ cnt, int B, int K1,
                                               int* __restrict__ base, int* __restrict__ bucketBase,
                                               int* __restrict__ bucketCnt) {
    __shared__ int sm[512];
    int k = threadIdx.x;
    int tot = 0;
    if (k < K1)
        for (int b = 0; b < B; b++) tot += cnt[b * K1 + k];   // row-coalesced across threads
    sm[k] = tot;
    __syncthreads();
    for (int off = 1; off < 512; off <<= 1) {
        int add = (k >= off) ? sm[k - off] : 0;
        __syncthreads();
        sm[k] += add;
        __syncthreads();
    }
    int excl = sm[k] - tot;
    if (k < K1) {
        bucketBase[k] = excl;
        bucketCnt[k] = tot;
        int run = excl;
        for (int b = 0; b < B; b++) {
            base[b * K1 + k] = run;        // row-coalesced
            run += cnt[b * K1 + k];
        }
    }
}

// ---------------- P3: per-block LDS counting sort, line-complete streaming output ----------------
__global__ __launch_bounds__(512) void k_csort(const int* __restrict__ ei, int E, int K1,
                                               const int* __restrict__ base, unsigned* __restrict__ part) {
    __shared__ unsigned sorted[12544];
    __shared__ int h[512], lb[512], cur[512], gb[512];
    int t = threadIdx.x;
    int e0 = blockIdx.x * PER, e1 = min(E, e0 + PER);
    int C = e1 - e0;
    h[t] = 0;
    __syncthreads();
    for (int e = e0 + t; e < e1; e += 512)
        atomicAdd(&h[ei[(size_t)E + e] >> CB_SHIFT], 1);
    __syncthreads();
    int v = h[t];
    lb[t] = v;
    __syncthreads();
    for (int off = 1; off < 512; off <<= 1) {
        int add = (t >= off) ? lb[t - off] : 0;
        __syncthreads();
        lb[t] += add;
        __syncthreads();
    }
    int excl = lb[t] - v;
    __syncthreads();
    lb[t] = excl;
    cur[t] = excl;
    if (t < K1) gb[t] = base[blockIdx.x * K1 + t];
    __syncthreads();
    for (int e = e0 + t; e < e1; e += 512) {
        int s = ei[e];
        int d = ei[(size_t)E + e];
        int pos = atomicAdd(&cur[d >> CB_SHIFT], 1);           // LDS atomic
        sorted[pos] = ((unsigned)s << CB_SHIFT) | (unsigned)(d & (CB_W - 1));
    }
    __syncthreads();
    // stream out in position order: consecutive i -> consecutive global addresses per bucket run
    for (int i = t; i < C; i += 512) {
        int lo = 0, hi = K1 - 1;
        while (lo < hi) {                                       // last k with lb[k] <= i
            int mid = (lo + hi + 1) >> 1;
            if (lb[mid] <= i) lo = mid; else hi = mid - 1;
        }
        part[(size_t)gb[lo] + (i - lb[lo])] = sorted[i];
    }
}

// ---------------- P4: per coarse bucket: node hist/dinv/offsets + CSR ----------------
__global__ __launch_bounds__(256) void k_prep2(const unsigned* __restrict__ part,
                                               const int* __restrict__ bucketBase, const int* __restrict__ bucketCnt,
                                               int* __restrict__ hist, float* __restrict__ dinv,
                                               int* __restrict__ offsets, int* __restrict__ csr, int N) {
    __shared__ int fh[CB_W], fb[CB_W], cur[CB_W];
    int k = blockIdx.x, t = threadIdx.x;
    int base = bucketBase[k], cnt = bucketCnt[k];
    int d0 = k << CB_SHIFT;
    fh[t] = 0;
    __syncthreads();
    for (int i = t; i < cnt; i += 256)
        atomicAdd(&fh[part[(size_t)base + i] & (CB_W - 1)], 1);  // LDS atomic
    __syncthreads();
    int v = fh[t];
    fb[t] = v;
    __syncthreads();
    for (int off = 1; off < 256; off <<= 1) {
        int add = (t >= off) ? fb[t - off] : 0;
        __syncthreads();
        fb[t] += add;
        __syncthreads();
    }
    int excl = fb[t] - v;
    int n = d0 + t;
    if (n < N) {
        offsets[n] = base + excl;
        hist[n] = v;
        dinv[n] = rsqrtf((float)(v + 1));
    }
    cur[t] = excl;
    __syncthreads();
    for (int i = t; i < cnt; i += 256) {
        unsigned e = part[(size_t)base + i];
        int pos = atomicAdd(&cur[e & (CB_W - 1)], 1);
        csr[(size_t)base + pos] = (int)(e >> CB_SHIFT);          // 4B scatter inside 33KB 1-block window
    }
}

// ---------------- K5: xw1' = dinv[n] * (x @ W1)  (v2: unique coalesced loads, deep ILP) ----------------
// wave = 4 groups x 16 j-lanes; each group owns 4 nodes; block = 4 waves = 64 nodes.
__global__ __launch_bounds__(256) void k_gemm1(const float* __restrict__ x, const float* __restrict__ W1,
                                               const float* __restrict__ dinv, float* __restrict__ xw1p, int N) {
    __shared__ float4 Wt[128 * 16];   // 32KB exactly: Wt[(c<<4)|j].w = W1[(4c+w)*16 + j]
    for (int idx = threadIdx.x; idx < 128 * 16; idx += 256) {
        int c = idx >> 4, j = idx & 15;
        int b = (4 * c) * 16 + j;
        Wt[idx] = make_float4(W1[b], W1[b + 16], W1[b + 32], W1[b + 48]);
    }
    __syncthreads();

    int lane = threadIdx.x & 63;
    int wave = threadIdx.x >> 6;
    int grp  = lane >> 4;
    int j    = lane & 15;
    int nodeBase = blockIdx.x * 64 + wave * 16 + grp * 4;

    const float4* xr0 = (const float4*)(x + (size_t)min(nodeBase + 0, N - 1) * F_IN);
    const float4* xr1 = (const float4*)(x + (size_t)min(nodeBase + 1, N - 1) * F_IN);
    const float4* xr2 = (const float4*)(x + (size_t)min(nodeBase + 2, N - 1) * F_IN);
    const float4* xr3 = (const float4*)(x + (size_t)min(nodeBase + 3, N - 1) * F_IN);

    float a0 = 0.f, a1 = 0.f, a2 = 0.f, a3 = 0.f;
    const float4* wr = &Wt[j];
#pragma unroll 2
    for (int c = 0; c < 128; c++) {
        float4 x0 = xr0[c];
        float4 x1 = xr1[c];
        float4 x2 = xr2[c];
        float4 x3 = xr3[c];
        float4 wv = wr[c << 4];
        a0 += x0.x * wv.x + x0.y * wv.y + x0.z * wv.z + x0.w * wv.w;
        a1 += x1.x * wv.x + x1.y * wv.y + x1.z * wv.z + x1.w * wv.w;
        a2 += x2.x * wv.x + x2.y * wv.y + x2.z * wv.z + x2.w * wv.w;
        a3 += x3.x * wv.x + x3.y * wv.y + x3.z * wv.z + x3.w * wv.w;
    }
    if (nodeBase + 0 < N) xw1p[(size_t)(nodeBase + 0) * F_OUT + j] = dinv[nodeBase + 0] * a0;
    if (nodeBase + 1 < N) xw1p[(size_t)(nodeBase + 1) * F_OUT + j] = dinv[nodeBase + 1] * a1;
    if (nodeBase + 2 < N) xw1p[(size_t)(nodeBase + 2) * F_OUT + j] = dinv[nodeBase + 2] * a2;
    if (nodeBase + 3 < N) xw1p[(size_t)(nodeBase + 3) * F_OUT + j] = dinv[nodeBase + 3] * a3;
}

// ---------------- K6: agg1 + bias + ReLU + fused (h @ W2) * dinv ----------------
__global__ __launch_bounds__(256) void k_agg1(const float* __restrict__ xw, const int* __restrict__ offsets,
                                              const int* __restrict__ hist, const float* __restrict__ dinv,
                                              const int* __restrict__ csr, const float* __restrict__ b1,
                                              const float* __restrict__ W2, float* __restrict__ xw2p, int N) {
    __shared__ float W2s[256];
    if (threadIdx.x < 256) W2s[threadIdx.x] = W2[threadIdx.x];
    __syncthreads();

    int lane = threadIdx.x & 63;
    int wave = threadIdx.x >> 6;
    int grp  = lane >> 4;
    int j    = lane & 15;
    int node = blockIdx.x * 16 + wave * 4 + grp;
    if (node >= N) return;

    float dn = dinv[node];
    float acc = xw[(size_t)node * F_OUT + j];
    float acc2 = 0.0f;
    int start = offsets[node], cnt = hist[node];
    int i = 0;
    for (; i + 2 <= cnt; i += 2) {
        int s0 = csr[start + i];
        int s1 = csr[start + i + 1];
        acc  += xw[(size_t)s0 * F_OUT + j];
        acc2 += xw[(size_t)s1 * F_OUT + j];
    }
    if (i < cnt) acc += xw[(size_t)csr[start + i] * F_OUT + j];

    float h = fmaxf(dn * (acc + acc2) + b1[j], 0.0f);

    float o = 0.0f;
    int base = lane & 48;
#pragma unroll
    for (int r = 0; r < 16; r++) {
        float hr = __shfl(h, base + r);
        o += hr * W2s[r * 16 + j];
    }
    xw2p[(size_t)node * F_OUT + j] = dn * o;
}

// ---------------- K7: agg2 + bias + ReLU + fused mean-pool partials ----------------
__global__ __launch_bounds__(256) void k_agg2(const float* __restrict__ xw, const int* __restrict__ offsets,
                                              const int* __restrict__ hist, const float* __restrict__ dinv,
                                              const int* __restrict__ csr, const float* __restrict__ b2,
                                              float* __restrict__ partials, int N) {
    int lane = threadIdx.x & 63;
    int wave = threadIdx.x >> 6;
    int grp  = lane >> 4;
    int j    = lane & 15;
    int node = blockIdx.x * 16 + wave * 4 + grp;

    float r = 0.0f;
    if (node < N) {
        float dn = dinv[node];
        float acc = xw[(size_t)node * F_OUT + j];
        float acc2 = 0.0f;
        int start = offsets[node], cnt = hist[node];
        int i = 0;
        for (; i + 2 <= cnt; i += 2) {
            int s0 = csr[start + i];
            int s1 = csr[start + i + 1];
            acc  += xw[(size_t)s0 * F_OUT + j];
            acc2 += xw[(size_t)s1 * F_OUT + j];
        }
        if (i < cnt) acc += xw[(size_t)csr[start + i] * F_OUT + j];
        r = fmaxf(dn * (acc + acc2) + b2[j], 0.0f);
    }
    r += __shfl_xor(r, 16);
    r += __shfl_xor(r, 32);
    __shared__ float sm[4][16];
    if (lane < 16) sm[wave][j] = r;
    __syncthreads();
    if (threadIdx.x < 16) {
        float s = sm[0][threadIdx.x] + sm[1][threadIdx.x] + sm[2][threadIdx.x] + sm[3][threadIdx.x];
        partials[(size_t)blockIdx.x * 16 + threadIdx.x] = s;
    }
}

// ---------------- K8: final reduce + fc ----------------
__global__ void k_final(const float* __restrict__ partials, int NB, const float* __restrict__ fc_w,
                        const float* __restrict__ fc_b, float* __restrict__ out, float invN) {
    __shared__ float sm[64][16];
    int t = threadIdx.x;  // 1024 threads
    int g = t >> 4, j = t & 15;
    float s = 0.0f;
    for (int bk = g; bk < NB; bk += 64) s += partials[(size_t)bk * 16 + j];
    sm[g][j] = s;
    __syncthreads();
    for (int str = 32; str > 0; str >>= 1) {
        if (g < str) sm[g][j] += sm[g + str][j];
        __syncthreads();
    }
    if (t == 0) {
        float acc = fc_b[0];
#pragma unroll
        for (int jj = 0; jj < 16; jj++) acc += sm[0][jj] * invN * fc_w[jj];
        out[0] = acc;
    }
}

extern "C" void kernel_launch(void* const* d_in, const int* in_sizes, int n_in,
                              void* d_out, int out_size, void* d_ws, size_t ws_size,
                              hipStream_t stream) {
    const float* x   = (const float*)d_in[0];
    const int*   ei  = (const int*)d_in[1];
    const float* W1  = (const float*)d_in[2];
    const float* b1  = (const float*)d_in[3];
    const float* W2  = (const float*)d_in[4];
    const float* b2  = (const float*)d_in[5];
    const float* fcw = (const float*)d_in[6];
    const float* fcb = (const float*)d_in[7];
    float* out = (float*)d_out;

    int N = in_sizes[0] / F_IN;            // 100000
    int E = in_sizes[1] / 2;               // 3200000
    int K1 = (N + CB_W - 1) >> CB_SHIFT;   // 391 coarse buckets
    int B1 = (E + PER - 1) / PER;          // 256 partition blocks

    // ---- workspace carve-up (256B aligned) ----
    char* p = (char*)d_ws;
    auto alloc = [&](size_t bytes) {
        void* r = (void*)p;
        p += (bytes + 255) & ~(size_t)255;
        return r;
    };
    int*   cnt        = (int*)alloc((size_t)B1 * K1 * 4);
    int*   base       = (int*)alloc((size_t)B1 * K1 * 4);
    int*   bucketBase = (int*)alloc((size_t)K1 * 4);
    int*   bucketCnt  = (int*)alloc((size_t)K1 * 4);
    int*   hist       = (int*)alloc((size_t)N * 4);
    int*   offsets    = (int*)alloc((size_t)N * 4);
    float* dinv       = (float*)alloc((size_t)N * 4);
    int*   csr        = (int*)alloc((size_t)E * 4);
    unsigned* part    = (unsigned*)alloc((size_t)E * 4);    // 12.8 MB
    int NB_NODE = (N + 15) / 16;                            // 6250
    float* partials = (float*)alloc((size_t)NB_NODE * 16 * 4);
    // alias: part region reused for xw after k_prep2 (2*N*16*4 == E*4)
    float* xw1p = (float*)part;
    float* xw2p = xw1p + (size_t)N * F_OUT;

    k_chist<<<B1, 256, 0, stream>>>(ei, E, K1, cnt);
    k_cscan<<<1, 512, 0, stream>>>(cnt, B1, K1, base, bucketBase, bucketCnt);
    k_csort<<<B1, 512, 0, stream>>>(ei, E, K1, base, part);
    k_prep2<<<K1, 256, 0, stream>>>(part, bucketBase, bucketCnt, hist, dinv, offsets, csr, N);

    k_gemm1<<<(N + 63) / 64, 256, 0, stream>>>(x, W1, dinv, xw1p, N);
    k_agg1<<<NB_NODE, 256, 0, stream>>>(xw1p, offsets, hist, dinv, csr, b1, W2, xw2p, N);
    k_agg2<<<NB_NODE, 256, 0, stream>>>(xw2p, offsets, hist, dinv, csr, b2, partials, N);
    k_final<<<1, 1024, 0, stream>>>(partials, NB_NODE, fcw, fcb, out, 1.0f / (float)N);
}

// Round 6
// 391.787 us; speedup vs baseline: 2.1252x; 1.0659x over previous
//
#include <hip/hip_runtime.h>
#include <stdint.h>

#define F_IN 512
#define F_OUT 16
#define CB_SHIFT 8
#define CB_W 256          // nodes per coarse bucket
#define PER 12500         // edges per partition block

// ---------------- P1: per-block LDS histogram over coarse buckets ----------------
__global__ __launch_bounds__(256) void k_chist(const int* __restrict__ ei, int E, int K1,
                                               int* __restrict__ cnt) {
    __shared__ int h[512];
    int t = threadIdx.x;
    for (int i = t; i < K1; i += 256) h[i] = 0;
    __syncthreads();
    int e0 = blockIdx.x * PER, e1 = min(E, e0 + PER);
    for (int e = e0 + t; e < e1; e += 256)
        atomicAdd(&h[ei[(size_t)E + e] >> CB_SHIFT], 1);
    __syncthreads();
    for (int i = t; i < K1; i += 256) cnt[blockIdx.x * K1 + i] = h[i];
}

// ---------------- P2: column scan -> per-(block,bucket) bases (single block) ----------------
__global__ __launch_bounds__(512) void k_cscan(const int* __restrict__ cnt, int B, int K1,
                                               int* __restrict__ base, int* __restrict__ bucketBase,
                                               int* __restrict__ bucketCnt) {
    __shared__ int sm[512];
    int k = threadIdx.x;
    int tot = 0;
    if (k < K1)
        for (int b = 0; b < B; b++) tot += cnt[b * K1 + k];   // row-coalesced across threads
    sm[k] = tot;
    __syncthreads();
    for (int off = 1; off < 512; off <<= 1) {
        int add = (k >= off) ? sm[k - off] : 0;
        __syncthreads();
        sm[k] += add;
        __syncthreads();
    }
    int excl = sm[k] - tot;
    if (k < K1) {
        bucketBase[k] = excl;
        bucketCnt[k] = tot;
        int run = excl;
        for (int b = 0; b < B; b++) {
            base[b * K1 + k] = run;        // row-coalesced
            run += cnt[b * K1 + k];
        }
    }
}

// ---------------- P3: per-block LDS counting sort, line-complete streaming output ----------------
__global__ __launch_bounds__(512) void k_csort(const int* __restrict__ ei, int E, int K1,
                                               const int* __restrict__ base, unsigned* __restrict__ part) {
    __shared__ unsigned sorted[12544];
    __shared__ int h[512], lb[512], cur[512], gb[512];
    int t = threadIdx.x;
    int e0 = blockIdx.x * PER, e1 = min(E, e0 + PER);
    int C = e1 - e0;
    h[t] = 0;
    __syncthreads();
    for (int e = e0 + t; e < e1; e += 512)
        atomicAdd(&h[ei[(size_t)E + e] >> CB_SHIFT], 1);
    __syncthreads();
    int v = h[t];
    lb[t] = v;
    __syncthreads();
    for (int off = 1; off < 512; off <<= 1) {
        int add = (t >= off) ? lb[t - off] : 0;
        __syncthreads();
        lb[t] += add;
        __syncthreads();
    }
    int excl = lb[t] - v;
    __syncthreads();
    lb[t] = excl;
    cur[t] = excl;
    if (t < K1) gb[t] = base[blockIdx.x * K1 + t];
    __syncthreads();
    for (int e = e0 + t; e < e1; e += 512) {
        int s = ei[e];
        int d = ei[(size_t)E + e];
        int pos = atomicAdd(&cur[d >> CB_SHIFT], 1);           // LDS atomic
        sorted[pos] = ((unsigned)s << CB_SHIFT) | (unsigned)(d & (CB_W - 1));
    }
    __syncthreads();
    // stream out in position order: consecutive i -> consecutive global addresses per bucket run
    for (int i = t; i < C; i += 512) {
        int lo = 0, hi = K1 - 1;
        while (lo < hi) {                                       // last k with lb[k] <= i
            int mid = (lo + hi + 1) >> 1;
            if (lb[mid] <= i) lo = mid; else hi = mid - 1;
        }
        part[(size_t)gb[lo] + (i - lb[lo])] = sorted[i];
    }
}

// ---------------- P4: per coarse bucket: node hist/dinv/offsets + CSR ----------------
__global__ __launch_bounds__(256) void k_prep2(const unsigned* __restrict__ part,
                                               const int* __restrict__ bucketBase, const int* __restrict__ bucketCnt,
                                               int* __restrict__ hist, float* __restrict__ dinv,
                                               int* __restrict__ offsets, int* __restrict__ csr, int N) {
    __shared__ int fh[CB_W], fb[CB_W], cur[CB_W];
    int k = blockIdx.x, t = threadIdx.x;
    int base = bucketBase[k], cnt = bucketCnt[k];
    int d0 = k << CB_SHIFT;
    fh[t] = 0;
    __syncthreads();
    for (int i = t; i < cnt; i += 256)
        atomicAdd(&fh[part[(size_t)base + i] & (CB_W - 1)], 1);  // LDS atomic
    __syncthreads();
    int v = fh[t];
    fb[t] = v;
    __syncthreads();
    for (int off = 1; off < 256; off <<= 1) {
        int add = (t >= off) ? fb[t - off] : 0;
        __syncthreads();
        fb[t] += add;
        __syncthreads();
    }
    int excl = fb[t] - v;
    int n = d0 + t;
    if (n < N) {
        offsets[n] = base + excl;
        hist[n] = v;
        dinv[n] = rsqrtf((float)(v + 1));
    }
    cur[t] = excl;
    __syncthreads();
    for (int i = t; i < cnt; i += 256) {
        unsigned e = part[(size_t)base + i];
        int pos = atomicAdd(&cur[e & (CB_W - 1)], 1);
        csr[(size_t)base + pos] = (int)(e >> CB_SHIFT);          // 4B scatter inside 33KB 1-block window
    }
}

// ---------------- K5 v3: xw1' = dinv[n] * (x @ W1) ----------------
// thread = (node, k-half): per-lane DISTINCT global loads (own row), W broadcast from LDS.
__global__ __launch_bounds__(256) void k_gemm1(const float* __restrict__ x, const float* __restrict__ W1,
                                               const float* __restrict__ dinv, float* __restrict__ xw1p, int N) {
    __shared__ float Ws[F_IN * F_OUT];        // 32 KB, layout [k][j] (same as W1)
    __shared__ float red[128 * 17];           // k-half reduction, padded (bank-spread)
    for (int idx = threadIdx.x; idx < F_IN * F_OUT; idx += 256)
        Ws[idx] = W1[idx];
    __syncthreads();

    int tl   = threadIdx.x & 127;
    int half = threadIdx.x >> 7;
    int n    = blockIdx.x * 128 + tl;
    int nc   = min(n, N - 1);

    const float4* xr = (const float4*)(x + (size_t)nc * F_IN + half * (F_IN / 2));
    const float4* wr = (const float4*)(Ws + half * (F_IN / 2) * F_OUT);

    float acc[F_OUT];
#pragma unroll
    for (int j = 0; j < F_OUT; j++) acc[j] = 0.f;

#pragma unroll 4
    for (int kk = 0; kk < F_IN / 8; kk++) {   // 64 iters; 4 k's per iter
        float4 xv = xr[kk];
#pragma unroll
        for (int i = 0; i < 4; i++) {
            float xs = (i == 0) ? xv.x : (i == 1) ? xv.y : (i == 2) ? xv.z : xv.w;
            const float4* wrow = wr + (kk * 4 + i) * 4;   // W row (uniform addr -> LDS broadcast)
#pragma unroll
            for (int q = 0; q < 4; q++) {
                float4 wv = wrow[q];
                acc[q * 4 + 0] = fmaf(xs, wv.x, acc[q * 4 + 0]);
                acc[q * 4 + 1] = fmaf(xs, wv.y, acc[q * 4 + 1]);
                acc[q * 4 + 2] = fmaf(xs, wv.z, acc[q * 4 + 2]);
                acc[q * 4 + 3] = fmaf(xs, wv.w, acc[q * 4 + 3]);
            }
        }
    }

    if (half == 1) {
#pragma unroll
        for (int j = 0; j < F_OUT; j++) red[tl * 17 + j] = acc[j];
    }
    __syncthreads();
    if (half == 0 && n < N) {
        float dn = dinv[n];
        float4* orow = (float4*)(xw1p + (size_t)n * F_OUT);
#pragma unroll
        for (int q = 0; q < 4; q++) {
            float4 o;
            o.x = dn * (acc[q * 4 + 0] + red[tl * 17 + q * 4 + 0]);
            o.y = dn * (acc[q * 4 + 1] + red[tl * 17 + q * 4 + 1]);
            o.z = dn * (acc[q * 4 + 2] + red[tl * 17 + q * 4 + 2]);
            o.w = dn * (acc[q * 4 + 3] + red[tl * 17 + q * 4 + 3]);
            orow[q] = o;
        }
    }
}

// ---------------- K6: agg1 + bias + ReLU + fused (h @ W2) * dinv ----------------
__global__ __launch_bounds__(256) void k_agg1(const float* __restrict__ xw, const int* __restrict__ offsets,
                                              const int* __restrict__ hist, const float* __restrict__ dinv,
                                              const int* __restrict__ csr, const float* __restrict__ b1,
                                              const float* __restrict__ W2, float* __restrict__ xw2p, int N) {
    __shared__ float W2s[256];
    if (threadIdx.x < 256) W2s[threadIdx.x] = W2[threadIdx.x];
    __syncthreads();

    int lane = threadIdx.x & 63;
    int wave = threadIdx.x >> 6;
    int grp  = lane >> 4;
    int j    = lane & 15;
    int node = blockIdx.x * 16 + wave * 4 + grp;
    if (node >= N) return;

    float dn = dinv[node];
    float acc = xw[(size_t)node * F_OUT + j];
    float acc2 = 0.0f;
    int start = offsets[node], cnt = hist[node];
    int i = 0;
    for (; i + 2 <= cnt; i += 2) {
        int s0 = csr[start + i];
        int s1 = csr[start + i + 1];
        acc  += xw[(size_t)s0 * F_OUT + j];
        acc2 += xw[(size_t)s1 * F_OUT + j];
    }
    if (i < cnt) acc += xw[(size_t)csr[start + i] * F_OUT + j];

    float h = fmaxf(dn * (acc + acc2) + b1[j], 0.0f);

    float o = 0.0f;
    int base = lane & 48;
#pragma unroll
    for (int r = 0; r < 16; r++) {
        float hr = __shfl(h, base + r);
        o += hr * W2s[r * 16 + j];
    }
    xw2p[(size_t)node * F_OUT + j] = dn * o;
}

// ---------------- K7: agg2 + bias + ReLU + fused mean-pool partials ----------------
__global__ __launch_bounds__(256) void k_agg2(const float* __restrict__ xw, const int* __restrict__ offsets,
                                              const int* __restrict__ hist, const float* __restrict__ dinv,
                                              const int* __restrict__ csr, const float* __restrict__ b2,
                                              float* __restrict__ partials, int N) {
    int lane = threadIdx.x & 63;
    int wave = threadIdx.x >> 6;
    int grp  = lane >> 4;
    int j    = lane & 15;
    int node = blockIdx.x * 16 + wave * 4 + grp;

    float r = 0.0f;
    if (node < N) {
        float dn = dinv[node];
        float acc = xw[(size_t)node * F_OUT + j];
        float acc2 = 0.0f;
        int start = offsets[node], cnt = hist[node];
        int i = 0;
        for (; i + 2 <= cnt; i += 2) {
            int s0 = csr[start + i];
            int s1 = csr[start + i + 1];
            acc  += xw[(size_t)s0 * F_OUT + j];
            acc2 += xw[(size_t)s1 * F_OUT + j];
        }
        if (i < cnt) acc += xw[(size_t)csr[start + i] * F_OUT + j];
        r = fmaxf(dn * (acc + acc2) + b2[j], 0.0f);
    }
    r += __shfl_xor(r, 16);
    r += __shfl_xor(r, 32);
    __shared__ float sm[4][16];
    if (lane < 16) sm[wave][j] = r;
    __syncthreads();
    if (threadIdx.x < 16) {
        float s = sm[0][threadIdx.x] + sm[1][threadIdx.x] + sm[2][threadIdx.x] + sm[3][threadIdx.x];
        partials[(size_t)blockIdx.x * 16 + threadIdx.x] = s;
    }
}

// ---------------- K8: final reduce + fc ----------------
__global__ void k_final(const float* __restrict__ partials, int NB, const float* __restrict__ fc_w,
                        const float* __restrict__ fc_b, float* __restrict__ out, float invN) {
    __shared__ float sm[64][16];
    int t = threadIdx.x;  // 1024 threads
    int g = t >> 4, j = t & 15;
    float s = 0.0f;
    for (int bk = g; bk < NB; bk += 64) s += partials[(size_t)bk * 16 + j];
    sm[g][j] = s;
    __syncthreads();
    for (int str = 32; str > 0; str >>= 1) {
        if (g < str) sm[g][j] += sm[g + str][j];
        __syncthreads();
    }
    if (t == 0) {
        float acc = fc_b[0];
#pragma unroll
        for (int jj = 0; jj < 16; jj++) acc += sm[0][jj] * invN * fc_w[jj];
        out[0] = acc;
    }
}

extern "C" void kernel_launch(void* const* d_in, const int* in_sizes, int n_in,
                              void* d_out, int out_size, void* d_ws, size_t ws_size,
                              hipStream_t stream) {
    const float* x   = (const float*)d_in[0];
    const int*   ei  = (const int*)d_in[1];
    const float* W1  = (const float*)d_in[2];
    const float* b1  = (const float*)d_in[3];
    const float* W2  = (const float*)d_in[4];
    const float* b2  = (const float*)d_in[5];
    const float* fcw = (const float*)d_in[6];
    const float* fcb = (const float*)d_in[7];
    float* out = (float*)d_out;

    int N = in_sizes[0] / F_IN;            // 100000
    int E = in_sizes[1] / 2;               // 3200000
    int K1 = (N + CB_W - 1) >> CB_SHIFT;   // 391 coarse buckets
    int B1 = (E + PER - 1) / PER;          // 256 partition blocks

    // ---- workspace carve-up (256B aligned) ----
    char* p = (char*)d_ws;
    auto alloc = [&](size_t bytes) {
        void* r = (void*)p;
        p += (bytes + 255) & ~(size_t)255;
        return r;
    };
    int*   cnt        = (int*)alloc((size_t)B1 * K1 * 4);
    int*   base       = (int*)alloc((size_t)B1 * K1 * 4);
    int*   bucketBase = (int*)alloc((size_t)K1 * 4);
    int*   bucketCnt  = (int*)alloc((size_t)K1 * 4);
    int*   hist       = (int*)alloc((size_t)N * 4);
    int*   offsets    = (int*)alloc((size_t)N * 4);
    float* dinv       = (float*)alloc((size_t)N * 4);
    int*   csr        = (int*)alloc((size_t)E * 4);
    unsigned* part    = (unsigned*)alloc((size_t)E * 4);    // 12.8 MB
    int NB_NODE = (N + 15) / 16;                            // 6250
    float* partials = (float*)alloc((size_t)NB_NODE * 16 * 4);
    // alias: part region reused for xw after k_prep2 (2*N*16*4 == E*4)
    float* xw1p = (float*)part;
    float* xw2p = xw1p + (size_t)N * F_OUT;

    k_chist<<<B1, 256, 0, stream>>>(ei, E, K1, cnt);
    k_cscan<<<1, 512, 0, stream>>>(cnt, B1, K1, base, bucketBase, bucketCnt);
    k_csort<<<B1, 512, 0, stream>>>(ei, E, K1, base, part);
    k_prep2<<<K1, 256, 0, stream>>>(part, bucketBase, bucketCnt, hist, dinv, offsets, csr, N);

    k_gemm1<<<(N + 127) / 128, 256, 0, stream>>>(x, W1, dinv, xw1p, N);
    k_agg1<<<NB_NODE, 256, 0, stream>>>(xw1p, offsets, hist, dinv, csr, b1, W2, xw2p, N);
    k_agg2<<<NB_NODE, 256, 0, stream>>>(xw2p, offsets, hist, dinv, csr, b2, partials, N);
    k_final<<<1, 1024, 0, stream>>>(partials, NB_NODE, fcw, fcb, out, 1.0f / (float)N);
}

// Round 7
// 281.947 us; speedup vs baseline: 2.9531x; 1.3896x over previous
//
#include <hip/hip_runtime.h>
#include <stdint.h>

#define F_IN 512
#define F_OUT 16
#define CB_SHIFT 8
#define CB_W 256          // nodes per coarse bucket
#define PER 12500         // edges per partition block

__device__ inline float4 f4_shfl_xor(float4 v, int mask) {
    float4 r;
    r.x = __shfl_xor(v.x, mask);
    r.y = __shfl_xor(v.y, mask);
    r.z = __shfl_xor(v.z, mask);
    r.w = __shfl_xor(v.w, mask);
    return r;
}

// ---------------- P1: per-block LDS histogram over coarse buckets (TRANSPOSED out) ----------------
__global__ __launch_bounds__(256) void k_chist(const int* __restrict__ ei, int E, int K1, int B,
                                               int* __restrict__ cntT) {
    __shared__ int h[512];
    int t = threadIdx.x;
    for (int i = t; i < K1; i += 256) h[i] = 0;
    __syncthreads();
    int e0 = blockIdx.x * PER, e1 = min(E, e0 + PER);
    for (int e = e0 + t; e < e1; e += 256)
        atomicAdd(&h[ei[(size_t)E + e] >> CB_SHIFT], 1);
    __syncthreads();
    for (int i = t; i < K1; i += 256) cntT[(size_t)i * B + blockIdx.x] = h[i];
}

// ---------------- P2a: per-bucket totals + scan over K1 (single block) ----------------
__global__ __launch_bounds__(512) void k_btot(const int* __restrict__ cntT, int B, int K1,
                                              int* __restrict__ bucketBase, int* __restrict__ bucketCnt) {
    __shared__ int sm[512];
    int k = threadIdx.x;
    int tot = 0;
    if (k < K1) {
        const int* row = cntT + (size_t)k * B;
        for (int b = 0; b < B; b++) tot += row[b];   // consecutive per thread
    }
    sm[k] = tot;
    __syncthreads();
    for (int off = 1; off < 512; off <<= 1) {
        int add = (k >= off) ? sm[k - off] : 0;
        __syncthreads();
        sm[k] += add;
        __syncthreads();
    }
    if (k < K1) { bucketBase[k] = sm[k] - tot; bucketCnt[k] = tot; }
}

// ---------------- P2b: per-(bucket,block) bases — coalesced scan per bucket ----------------
__global__ __launch_bounds__(256) void k_bbase(const int* __restrict__ cntT, int B,
                                               const int* __restrict__ bucketBase,
                                               int* __restrict__ baseT) {
    __shared__ int sm[256];
    int k = blockIdx.x, t = threadIdx.x;
    int v = (t < B) ? cntT[(size_t)k * B + t] : 0;
    sm[t] = v;
    __syncthreads();
    for (int off = 1; off < 256; off <<= 1) {
        int add = (t >= off) ? sm[t - off] : 0;
        __syncthreads();
        sm[t] += add;
        __syncthreads();
    }
    if (t < B) baseT[(size_t)k * B + t] = bucketBase[k] + sm[t] - v;  // exclusive
}

// ---------------- P3: per-block LDS counting sort, line-complete streaming output ----------------
__global__ __launch_bounds__(512) void k_csort(const int* __restrict__ ei, int E, int K1, int B,
                                               const int* __restrict__ baseT, unsigned* __restrict__ part) {
    __shared__ unsigned sorted[12544];
    __shared__ int h[512], lb[512], cur[512], gb[512];
    int t = threadIdx.x;
    int e0 = blockIdx.x * PER, e1 = min(E, e0 + PER);
    int C = e1 - e0;
    h[t] = 0;
    __syncthreads();
    for (int e = e0 + t; e < e1; e += 512)
        atomicAdd(&h[ei[(size_t)E + e] >> CB_SHIFT], 1);
    __syncthreads();
    int v = h[t];
    lb[t] = v;
    __syncthreads();
    for (int off = 1; off < 512; off <<= 1) {
        int add = (t >= off) ? lb[t - off] : 0;
        __syncthreads();
        lb[t] += add;
        __syncthreads();
    }
    int excl = lb[t] - v;
    __syncthreads();
    lb[t] = excl;
    cur[t] = excl;
    if (t < K1) gb[t] = baseT[(size_t)t * B + blockIdx.x];
    __syncthreads();
    for (int e = e0 + t; e < e1; e += 512) {
        int s = ei[e];
        int d = ei[(size_t)E + e];
        int pos = atomicAdd(&cur[d >> CB_SHIFT], 1);           // LDS atomic
        sorted[pos] = ((unsigned)s << CB_SHIFT) | (unsigned)(d & (CB_W - 1));
    }
    __syncthreads();
    for (int i = t; i < C; i += 512) {
        int lo = 0, hi = K1 - 1;
        while (lo < hi) {                                       // last k with lb[k] <= i
            int mid = (lo + hi + 1) >> 1;
            if (lb[mid] <= i) lo = mid; else hi = mid - 1;
        }
        part[(size_t)gb[lo] + (i - lb[lo])] = sorted[i];
    }
}

// ---------------- P4: per coarse bucket: node hist/dinv/offsets + CSR ----------------
__global__ __launch_bounds__(256) void k_prep2(const unsigned* __restrict__ part,
                                               const int* __restrict__ bucketBase, const int* __restrict__ bucketCnt,
                                               int* __restrict__ hist, float* __restrict__ dinv,
                                               int* __restrict__ offsets, int* __restrict__ csr, int N) {
    __shared__ int fh[CB_W], fb[CB_W], cur[CB_W];
    int k = blockIdx.x, t = threadIdx.x;
    int base = bucketBase[k], cnt = bucketCnt[k];
    int d0 = k << CB_SHIFT;
    fh[t] = 0;
    __syncthreads();
    for (int i = t; i < cnt; i += 256)
        atomicAdd(&fh[part[(size_t)base + i] & (CB_W - 1)], 1);
    __syncthreads();
    int v = fh[t];
    fb[t] = v;
    __syncthreads();
    for (int off = 1; off < 256; off <<= 1) {
        int add = (t >= off) ? fb[t - off] : 0;
        __syncthreads();
        fb[t] += add;
        __syncthreads();
    }
    int excl = fb[t] - v;
    int n = d0 + t;
    if (n < N) {
        offsets[n] = base + excl;
        hist[n] = v;
        dinv[n] = rsqrtf((float)(v + 1));
    }
    cur[t] = excl;
    __syncthreads();
    for (int i = t; i < cnt; i += 256) {
        unsigned e = part[(size_t)base + i];
        int pos = atomicAdd(&cur[e & (CB_W - 1)], 1);
        csr[(size_t)base + pos] = (int)(e >> CB_SHIFT);
    }
}

// ---------------- K5 v4: xw1' = dinv[n] * (x @ W1) — R=2 rows/thread, W in LDS ----------------
__global__ __launch_bounds__(128) void k_gemm1(const float* __restrict__ x, const float* __restrict__ W1,
                                               const float* __restrict__ dinv, float* __restrict__ xw1p, int N) {
    __shared__ float4 Wv[2048];   // 32 KB; Wv[k*4+q] = W1[k*16 + 4q .. +3]
    const float4* w1v = (const float4*)W1;
    for (int i = threadIdx.x; i < 2048; i += 128) Wv[i] = w1v[i];
    __syncthreads();

    int t = threadIdx.x;
    int n0 = blockIdx.x * 256 + t;
    int n1 = n0 + 128;
    const float4* xr0 = (const float4*)(x + (size_t)min(n0, N - 1) * F_IN);
    const float4* xr1 = (const float4*)(x + (size_t)min(n1, N - 1) * F_IN);

    float acc0[16], acc1[16];
#pragma unroll
    for (int j = 0; j < 16; j++) { acc0[j] = 0.f; acc1[j] = 0.f; }

#pragma unroll 2
    for (int kk = 0; kk < 128; kk++) {     // 4 k's per iter
        float4 x0 = xr0[kk];
        float4 x1 = xr1[kk];
        const float4* wr = &Wv[kk * 16];   // wave-uniform LDS
#pragma unroll
        for (int i = 0; i < 4; i++) {
            float xs0 = (i == 0) ? x0.x : (i == 1) ? x0.y : (i == 2) ? x0.z : x0.w;
            float xs1 = (i == 0) ? x1.x : (i == 1) ? x1.y : (i == 2) ? x1.z : x1.w;
#pragma unroll
            for (int q = 0; q < 4; q++) {
                float4 wv = wr[i * 4 + q];
                acc0[q*4+0] = fmaf(xs0, wv.x, acc0[q*4+0]);
                acc0[q*4+1] = fmaf(xs0, wv.y, acc0[q*4+1]);
                acc0[q*4+2] = fmaf(xs0, wv.z, acc0[q*4+2]);
                acc0[q*4+3] = fmaf(xs0, wv.w, acc0[q*4+3]);
                acc1[q*4+0] = fmaf(xs1, wv.x, acc1[q*4+0]);
                acc1[q*4+1] = fmaf(xs1, wv.y, acc1[q*4+1]);
                acc1[q*4+2] = fmaf(xs1, wv.z, acc1[q*4+2]);
                acc1[q*4+3] = fmaf(xs1, wv.w, acc1[q*4+3]);
            }
        }
    }
    if (n0 < N) {
        float dn = dinv[n0];
        float4* orow = (float4*)(xw1p + (size_t)n0 * F_OUT);
#pragma unroll
        for (int q = 0; q < 4; q++)
            orow[q] = make_float4(dn*acc0[q*4+0], dn*acc0[q*4+1], dn*acc0[q*4+2], dn*acc0[q*4+3]);
    }
    if (n1 < N) {
        float dn = dinv[n1];
        float4* orow = (float4*)(xw1p + (size_t)n1 * F_OUT);
#pragma unroll
        for (int q = 0; q < 4; q++)
            orow[q] = make_float4(dn*acc1[q*4+0], dn*acc1[q*4+1], dn*acc1[q*4+2], dn*acc1[q*4+3]);
    }
}

// ---------------- K6 v2: agg1 + bias + ReLU + fused (h @ W2) * dinv — float4 gathers ----------------
// 16-lane group per node: lane = eo*4 + q (4 edge slots x 4 quarters)
__global__ __launch_bounds__(256) void k_agg1(const float* __restrict__ xw, const int* __restrict__ offsets,
                                              const int* __restrict__ hist, const float* __restrict__ dinv,
                                              const int* __restrict__ csr, const float* __restrict__ b1,
                                              const float* __restrict__ W2, float* __restrict__ xw2p, int N) {
    __shared__ float W2s[256];
    if (threadIdx.x < 256) W2s[threadIdx.x] = W2[threadIdx.x];
    __syncthreads();

    int lane = threadIdx.x & 63;
    int wave = threadIdx.x >> 6;
    int grp  = lane >> 4;
    int sub  = lane & 15;
    int eo   = sub >> 2;
    int q    = sub & 3;
    int node = blockIdx.x * 16 + wave * 4 + grp;
    if (node >= N) return;

    int start = offsets[node], cnt = hist[node];
    float dn = dinv[node];
    float4 acc  = make_float4(0.f, 0.f, 0.f, 0.f);
    float4 acc2 = make_float4(0.f, 0.f, 0.f, 0.f);
    int i = 0;
    for (; i + 8 <= cnt; i += 8) {
        int s0 = csr[start + i + eo];
        int s1 = csr[start + i + 4 + eo];
        float4 v0 = ((const float4*)(xw + (size_t)s0 * F_OUT))[q];
        float4 v1 = ((const float4*)(xw + (size_t)s1 * F_OUT))[q];
        acc.x  += v0.x; acc.y  += v0.y; acc.z  += v0.z; acc.w  += v0.w;
        acc2.x += v1.x; acc2.y += v1.y; acc2.z += v1.z; acc2.w += v1.w;
    }
    for (; i < cnt; i += 4) {
        if (i + eo < cnt) {
            int s0 = csr[start + i + eo];
            float4 v0 = ((const float4*)(xw + (size_t)s0 * F_OUT))[q];
            acc.x += v0.x; acc.y += v0.y; acc.z += v0.z; acc.w += v0.w;
        }
    }
    acc.x += acc2.x; acc.y += acc2.y; acc.z += acc2.z; acc.w += acc2.w;
    { float4 u = f4_shfl_xor(acc, 4); acc.x+=u.x; acc.y+=u.y; acc.z+=u.z; acc.w+=u.w; }
    { float4 u = f4_shfl_xor(acc, 8); acc.x+=u.x; acc.y+=u.y; acc.z+=u.z; acc.w+=u.w; }

    float4 sv = ((const float4*)(xw + (size_t)node * F_OUT))[q];
    float4 bq = ((const float4*)b1)[q];
    float4 h;
    h.x = fmaxf(dn * (acc.x + sv.x) + bq.x, 0.f);
    h.y = fmaxf(dn * (acc.y + sv.y) + bq.y, 0.f);
    h.z = fmaxf(dn * (acc.z + sv.z) + bq.z, 0.f);
    h.w = fmaxf(dn * (acc.w + sv.w) + bq.w, 0.f);

    // fused 16x16 GEMM: o_j = sum_r h[r] * W2[r][j], j = sub
    float o = 0.f;
#pragma unroll
    for (int a = 0; a < 4; a++) {
        int src = (grp << 4) + a;   // lane with q==a, eo==0 holds quarter a
        float h0 = __shfl(h.x, src);
        float h1 = __shfl(h.y, src);
        float h2 = __shfl(h.z, src);
        float h3 = __shfl(h.w, src);
        o += h0 * W2s[(a*4+0)*16 + sub] + h1 * W2s[(a*4+1)*16 + sub]
           + h2 * W2s[(a*4+2)*16 + sub] + h3 * W2s[(a*4+3)*16 + sub];
    }
    xw2p[(size_t)node * F_OUT + sub] = dn * o;
}

// ---------------- K7 v2: agg2 + bias + ReLU + fused mean-pool partials ----------------
__global__ __launch_bounds__(256) void k_agg2(const float* __restrict__ xw, const int* __restrict__ offsets,
                                              const int* __restrict__ hist, const float* __restrict__ dinv,
                                              const int* __restrict__ csr, const float* __restrict__ b2,
                                              float* __restrict__ partials, int N) {
    int lane = threadIdx.x & 63;
    int wave = threadIdx.x >> 6;
    int grp  = lane >> 4;
    int sub  = lane & 15;
    int eo   = sub >> 2;
    int q    = sub & 3;
    int node = blockIdx.x * 16 + wave * 4 + grp;

    float4 m = make_float4(0.f, 0.f, 0.f, 0.f);
    if (node < N) {
        int start = offsets[node], cnt = hist[node];
        float dn = dinv[node];
        float4 acc  = make_float4(0.f, 0.f, 0.f, 0.f);
        float4 acc2 = make_float4(0.f, 0.f, 0.f, 0.f);
        int i = 0;
        for (; i + 8 <= cnt; i += 8) {
            int s0 = csr[start + i + eo];
            int s1 = csr[start + i + 4 + eo];
            float4 v0 = ((const float4*)(xw + (size_t)s0 * F_OUT))[q];
            float4 v1 = ((const float4*)(xw + (size_t)s1 * F_OUT))[q];
            acc.x  += v0.x; acc.y  += v0.y; acc.z  += v0.z; acc.w  += v0.w;
            acc2.x += v1.x; acc2.y += v1.y; acc2.z += v1.z; acc2.w += v1.w;
        }
        for (; i < cnt; i += 4) {
            if (i + eo < cnt) {
                int s0 = csr[start + i + eo];
                float4 v0 = ((const float4*)(xw + (size_t)s0 * F_OUT))[q];
                acc.x += v0.x; acc.y += v0.y; acc.z += v0.z; acc.w += v0.w;
            }
        }
        acc.x += acc2.x; acc.y += acc2.y; acc.z += acc2.z; acc.w += acc2.w;
        { float4 u = f4_shfl_xor(acc, 4); acc.x+=u.x; acc.y+=u.y; acc.z+=u.z; acc.w+=u.w; }
        { float4 u = f4_shfl_xor(acc, 8); acc.x+=u.x; acc.y+=u.y; acc.z+=u.z; acc.w+=u.w; }
        float4 sv = ((const float4*)(xw + (size_t)node * F_OUT))[q];
        float4 bq = ((const float4*)b2)[q];
        if (eo == 0) {   // one copy per quarter for pooling
            m.x = fmaxf(dn * (acc.x + sv.x) + bq.x, 0.f);
            m.y = fmaxf(dn * (acc.y + sv.y) + bq.y, 0.f);
            m.z = fmaxf(dn * (acc.z + sv.z) + bq.z, 0.f);
            m.w = fmaxf(dn * (acc.w + sv.w) + bq.w, 0.f);
        }
    }
    // sum over the 4 groups (lane bits 4,5); eo!=0 lanes carry zeros
    { float4 u = f4_shfl_xor(m, 16); m.x+=u.x; m.y+=u.y; m.z+=u.z; m.w+=u.w; }
    { float4 u = f4_shfl_xor(m, 32); m.x+=u.x; m.y+=u.y; m.z+=u.z; m.w+=u.w; }
    __shared__ float smf[4][16];
    if (lane < 4) {   // lanes 0..3: eo=0, q=lane
        smf[wave][lane*4+0] = 0.f;  // placeholder, overwritten below (keep writes static)
        smf[wave][q*4+0] = m.x;
        smf[wave][q*4+1] = m.y;
        smf[wave][q*4+2] = m.z;
        smf[wave][q*4+3] = m.w;
    }
    __syncthreads();
    if (threadIdx.x < 16) {
        float s = smf[0][threadIdx.x] + smf[1][threadIdx.x] + smf[2][threadIdx.x] + smf[3][threadIdx.x];
        partials[(size_t)blockIdx.x * 16 + threadIdx.x] = s;
    }
}

// ---------------- K8: final reduce + fc ----------------
__global__ void k_final(const float* __restrict__ partials, int NB, const float* __restrict__ fc_w,
                        const float* __restrict__ fc_b, float* __restrict__ out, float invN) {
    __shared__ float sm[64][16];
    int t = threadIdx.x;  // 1024 threads
    int g = t >> 4, j = t & 15;
    float s = 0.0f;
    for (int bk = g; bk < NB; bk += 64) s += partials[(size_t)bk * 16 + j];
    sm[g][j] = s;
    __syncthreads();
    for (int str = 32; str > 0; str >>= 1) {
        if (g < str) sm[g][j] += sm[g + str][j];
        __syncthreads();
    }
    if (t == 0) {
        float acc = fc_b[0];
#pragma unroll
        for (int jj = 0; jj < 16; jj++) acc += sm[0][jj] * invN * fc_w[jj];
        out[0] = acc;
    }
}

extern "C" void kernel_launch(void* const* d_in, const int* in_sizes, int n_in,
                              void* d_out, int out_size, void* d_ws, size_t ws_size,
                              hipStream_t stream) {
    const float* x   = (const float*)d_in[0];
    const int*   ei  = (const int*)d_in[1];
    const float* W1  = (const float*)d_in[2];
    const float* b1  = (const float*)d_in[3];
    const float* W2  = (const float*)d_in[4];
    const float* b2  = (const float*)d_in[5];
    const float* fcw = (const float*)d_in[6];
    const float* fcb = (const float*)d_in[7];
    float* out = (float*)d_out;

    int N = in_sizes[0] / F_IN;            // 100000
    int E = in_sizes[1] / 2;               // 3200000
    int K1 = (N + CB_W - 1) >> CB_SHIFT;   // 391 coarse buckets
    int B1 = (E + PER - 1) / PER;          // 256 partition blocks

    // ---- workspace carve-up (256B aligned) ----
    char* p = (char*)d_ws;
    auto alloc = [&](size_t bytes) {
        void* r = (void*)p;
        p += (bytes + 255) & ~(size_t)255;
        return r;
    };
    int*   cntT       = (int*)alloc((size_t)K1 * B1 * 4);
    int*   baseT      = (int*)alloc((size_t)K1 * B1 * 4);
    int*   bucketBase = (int*)alloc((size_t)K1 * 4);
    int*   bucketCnt  = (int*)alloc((size_t)K1 * 4);
    int*   hist       = (int*)alloc((size_t)N * 4);
    int*   offsets    = (int*)alloc((size_t)N * 4);
    float* dinv       = (float*)alloc((size_t)N * 4);
    int*   csr        = (int*)alloc((size_t)E * 4);
    unsigned* part    = (unsigned*)alloc((size_t)E * 4);    // 12.8 MB
    int NB_NODE = (N + 15) / 16;                            // 6250
    float* partials = (float*)alloc((size_t)NB_NODE * 16 * 4);
    // alias: part region reused for xw after k_prep2 (2*N*16*4 == E*4)
    float* xw1p = (float*)part;
    float* xw2p = xw1p + (size_t)N * F_OUT;

    k_chist<<<B1, 256, 0, stream>>>(ei, E, K1, B1, cntT);
    k_btot<<<1, 512, 0, stream>>>(cntT, B1, K1, bucketBase, bucketCnt);
    k_bbase<<<K1, 256, 0, stream>>>(cntT, B1, bucketBase, baseT);
    k_csort<<<B1, 512, 0, stream>>>(ei, E, K1, B1, baseT, part);
    k_prep2<<<K1, 256, 0, stream>>>(part, bucketBase, bucketCnt, hist, dinv, offsets, csr, N);

    k_gemm1<<<(N + 255) / 256, 128, 0, stream>>>(x, W1, dinv, xw1p, N);
    k_agg1<<<NB_NODE, 256, 0, stream>>>(xw1p, offsets, hist, dinv, csr, b1, W2, xw2p, N);
    k_agg2<<<NB_NODE, 256, 0, stream>>>(xw2p, offsets, hist, dinv, csr, b2, partials, N);
    k_final<<<1, 1024, 0, stream>>>(partials, NB_NODE, fcw, fcb, out, 1.0f / (float)N);
}

// Round 8
// 258.609 us; speedup vs baseline: 3.2196x; 1.0902x over previous
//
#include <hip/hip_runtime.h>
#include <stdint.h>

#define F_IN 512
#define F_OUT 16
#define CB_SHIFT 8
#define CB_W 256          // nodes per coarse bucket
#define PER 6250          // edges per partition block (B1 = 512)
#define SORT_CAP 6400

__device__ inline float4 f4_shfl_xor(float4 v, int mask) {
    float4 r;
    r.x = __shfl_xor(v.x, mask);
    r.y = __shfl_xor(v.y, mask);
    r.z = __shfl_xor(v.z, mask);
    r.w = __shfl_xor(v.w, mask);
    return r;
}

// ---------------- P1: per-block LDS histogram over coarse buckets (TRANSPOSED out) ----------------
__global__ __launch_bounds__(256) void k_chist(const int* __restrict__ ei, int E, int K1, int B,
                                               int* __restrict__ cntT) {
    __shared__ int h[512];
    int t = threadIdx.x;
    for (int i = t; i < K1; i += 256) h[i] = 0;
    __syncthreads();
    int e0 = blockIdx.x * PER, e1 = min(E, e0 + PER);
    for (int e = e0 + t; e < e1; e += 256)
        atomicAdd(&h[ei[(size_t)E + e] >> CB_SHIFT], 1);
    __syncthreads();
    for (int i = t; i < K1; i += 256) cntT[(size_t)i * B + blockIdx.x] = h[i];
}

// ---------------- P2a: per-bucket totals + scan over K1 (single block) ----------------
__global__ __launch_bounds__(512) void k_btot(const int* __restrict__ cntT, int B, int K1,
                                              int* __restrict__ bucketBase, int* __restrict__ bucketCnt) {
    __shared__ int sm[512];
    int k = threadIdx.x;
    int tot = 0;
    if (k < K1) {
        const int4* row = (const int4*)(cntT + (size_t)k * B);
        for (int b = 0; b < B / 4; b++) {
            int4 v = row[b];
            tot += v.x + v.y + v.z + v.w;
        }
    }
    sm[k] = tot;
    __syncthreads();
    for (int off = 1; off < 512; off <<= 1) {
        int add = (k >= off) ? sm[k - off] : 0;
        __syncthreads();
        sm[k] += add;
        __syncthreads();
    }
    if (k < K1) { bucketBase[k] = sm[k] - tot; bucketCnt[k] = tot; }
}

// ---------------- P2b: per-(bucket,block) bases — coalesced scan per bucket ----------------
__global__ __launch_bounds__(512) void k_bbase(const int* __restrict__ cntT, int B,
                                               const int* __restrict__ bucketBase,
                                               int* __restrict__ baseT) {
    __shared__ int sm[512];
    int k = blockIdx.x, t = threadIdx.x;
    int v = (t < B) ? cntT[(size_t)k * B + t] : 0;
    sm[t] = v;
    __syncthreads();
    for (int off = 1; off < 512; off <<= 1) {
        int add = (t >= off) ? sm[t - off] : 0;
        __syncthreads();
        sm[t] += add;
        __syncthreads();
    }
    if (t < B) baseT[(size_t)k * B + t] = bucketBase[k] + sm[t] - v;  // exclusive
}

// ---------------- P3: per-block LDS counting sort, wave-per-bucket copy-out ----------------
__global__ __launch_bounds__(512) void k_csort(const int* __restrict__ ei, int E, int K1, int B,
                                               const int* __restrict__ baseT, unsigned* __restrict__ part) {
    __shared__ unsigned sorted[SORT_CAP];
    __shared__ int h[512], lb[512], cur[512], gb[512];
    int t = threadIdx.x;
    int e0 = blockIdx.x * PER, e1 = min(E, e0 + PER);
    int C = e1 - e0;
    h[t] = 0;
    __syncthreads();
    for (int e = e0 + t; e < e1; e += 512)
        atomicAdd(&h[ei[(size_t)E + e] >> CB_SHIFT], 1);
    __syncthreads();
    int v = h[t];
    lb[t] = v;
    __syncthreads();
    for (int off = 1; off < 512; off <<= 1) {
        int add = (t >= off) ? lb[t - off] : 0;
        __syncthreads();
        lb[t] += add;
        __syncthreads();
    }
    int excl = lb[t] - v;
    __syncthreads();
    lb[t] = excl;
    cur[t] = excl;
    if (t < K1) gb[t] = baseT[(size_t)t * B + blockIdx.x];
    __syncthreads();
    for (int e = e0 + t; e < e1; e += 512) {
        int s = ei[e];
        int d = ei[(size_t)E + e];
        int pos = atomicAdd(&cur[d >> CB_SHIFT], 1);           // LDS atomic
        sorted[pos] = ((unsigned)s << CB_SHIFT) | (unsigned)(d & (CB_W - 1));
    }
    __syncthreads();
    // wave-per-bucket copy-out: coalesced LDS reads, contiguous global writes per bucket run
    int wv = t >> 6, ln = t & 63;
    for (int k = wv; k < K1; k += 8) {
        int s0 = lb[k];
        int s1 = cur[k];          // after scatter, cur[k] == lb[k] + h[k]
        int g  = gb[k];
        for (int i = s0 + ln; i < s1; i += 64)
            part[(size_t)g + (i - s0)] = sorted[i];
    }
}

// ---------------- P4: per coarse bucket: node hist/dinv/offsets + CSR (512 threads) ----------------
__global__ __launch_bounds__(512) void k_prep2(const unsigned* __restrict__ part,
                                               const int* __restrict__ bucketBase, const int* __restrict__ bucketCnt,
                                               int* __restrict__ hist, float* __restrict__ dinv,
                                               int* __restrict__ offsets, int* __restrict__ csr, int N) {
    __shared__ int fh[CB_W], fb[CB_W], cur[CB_W];
    int k = blockIdx.x, t = threadIdx.x;
    int base = bucketBase[k], cnt = bucketCnt[k];
    int d0 = k << CB_SHIFT;
    if (t < CB_W) fh[t] = 0;
    __syncthreads();
    for (int i = t; i < cnt; i += 512)
        atomicAdd(&fh[part[(size_t)base + i] & (CB_W - 1)], 1);
    __syncthreads();
    int v = 0;
    if (t < CB_W) { v = fh[t]; fb[t] = v; }
    __syncthreads();
    for (int off = 1; off < CB_W; off <<= 1) {
        int add = (t >= off && t < CB_W) ? fb[t - off] : 0;
        __syncthreads();
        if (t < CB_W) fb[t] += add;
        __syncthreads();
    }
    if (t < CB_W) {
        int excl = fb[t] - v;
        int n = d0 + t;
        if (n < N) {
            offsets[n] = base + excl;
            hist[n] = v;
            dinv[n] = rsqrtf((float)(v + 1));
        }
        cur[t] = excl;
    }
    __syncthreads();
    for (int i = t; i < cnt; i += 512) {
        unsigned e = part[(size_t)base + i];
        int pos = atomicAdd(&cur[e & (CB_W - 1)], 1);
        csr[(size_t)base + pos] = (int)(e >> CB_SHIFT);
    }
}

// ---------------- K5 v4: xw1' = dinv[n] * (x @ W1) — R=2 rows/thread, W in LDS ----------------
__global__ __launch_bounds__(128) void k_gemm1(const float* __restrict__ x, const float* __restrict__ W1,
                                               const float* __restrict__ dinv, float* __restrict__ xw1p, int N) {
    __shared__ float4 Wv[2048];   // 32 KB; Wv[k*4+q] = W1[k*16 + 4q .. +3]
    const float4* w1v = (const float4*)W1;
    for (int i = threadIdx.x; i < 2048; i += 128) Wv[i] = w1v[i];
    __syncthreads();

    int t = threadIdx.x;
    int n0 = blockIdx.x * 256 + t;
    int n1 = n0 + 128;
    const float4* xr0 = (const float4*)(x + (size_t)min(n0, N - 1) * F_IN);
    const float4* xr1 = (const float4*)(x + (size_t)min(n1, N - 1) * F_IN);

    float acc0[16], acc1[16];
#pragma unroll
    for (int j = 0; j < 16; j++) { acc0[j] = 0.f; acc1[j] = 0.f; }

#pragma unroll 2
    for (int kk = 0; kk < 128; kk++) {     // 4 k's per iter
        float4 x0 = xr0[kk];
        float4 x1 = xr1[kk];
        const float4* wr = &Wv[kk * 16];   // wave-uniform LDS
#pragma unroll
        for (int i = 0; i < 4; i++) {
            float xs0 = (i == 0) ? x0.x : (i == 1) ? x0.y : (i == 2) ? x0.z : x0.w;
            float xs1 = (i == 0) ? x1.x : (i == 1) ? x1.y : (i == 2) ? x1.z : x1.w;
#pragma unroll
            for (int q = 0; q < 4; q++) {
                float4 wv = wr[i * 4 + q];
                acc0[q*4+0] = fmaf(xs0, wv.x, acc0[q*4+0]);
                acc0[q*4+1] = fmaf(xs0, wv.y, acc0[q*4+1]);
                acc0[q*4+2] = fmaf(xs0, wv.z, acc0[q*4+2]);
                acc0[q*4+3] = fmaf(xs0, wv.w, acc0[q*4+3]);
                acc1[q*4+0] = fmaf(xs1, wv.x, acc1[q*4+0]);
                acc1[q*4+1] = fmaf(xs1, wv.y, acc1[q*4+1]);
                acc1[q*4+2] = fmaf(xs1, wv.z, acc1[q*4+2]);
                acc1[q*4+3] = fmaf(xs1, wv.w, acc1[q*4+3]);
            }
        }
    }
    if (n0 < N) {
        float dn = dinv[n0];
        float4* orow = (float4*)(xw1p + (size_t)n0 * F_OUT);
#pragma unroll
        for (int q = 0; q < 4; q++)
            orow[q] = make_float4(dn*acc0[q*4+0], dn*acc0[q*4+1], dn*acc0[q*4+2], dn*acc0[q*4+3]);
    }
    if (n1 < N) {
        float dn = dinv[n1];
        float4* orow = (float4*)(xw1p + (size_t)n1 * F_OUT);
#pragma unroll
        for (int q = 0; q < 4; q++)
            orow[q] = make_float4(dn*acc1[q*4+0], dn*acc1[q*4+1], dn*acc1[q*4+2], dn*acc1[q*4+3]);
    }
}

// ---------------- K6 v3: agg1 + bias + ReLU + fused (h @ W2) * dinv — 4-deep MLP ----------------
// 16-lane group per node: lane = eo*4 + q (4 edge slots x 4 quarters)
__global__ __launch_bounds__(256) void k_agg1(const float* __restrict__ xw, const int* __restrict__ offsets,
                                              const int* __restrict__ hist, const float* __restrict__ dinv,
                                              const int* __restrict__ csr, const float* __restrict__ b1,
                                              const float* __restrict__ W2, float* __restrict__ xw2p, int N) {
    __shared__ float W2s[256];
    if (threadIdx.x < 256) W2s[threadIdx.x] = W2[threadIdx.x];
    __syncthreads();

    int lane = threadIdx.x & 63;
    int wave = threadIdx.x >> 6;
    int grp  = lane >> 4;
    int sub  = lane & 15;
    int eo   = sub >> 2;
    int q    = sub & 3;
    int node = blockIdx.x * 16 + wave * 4 + grp;
    if (node >= N) return;

    int start = offsets[node], cnt = hist[node];
    float dn = dinv[node];
    float4 a0 = make_float4(0.f,0.f,0.f,0.f), a1 = a0, a2 = a0, a3 = a0;
    int i = 0;
    for (; i + 16 <= cnt; i += 16) {
        int s0 = csr[start + i + eo];
        int s1 = csr[start + i + 4 + eo];
        int s2 = csr[start + i + 8 + eo];
        int s3 = csr[start + i + 12 + eo];
        float4 v0 = ((const float4*)(xw + (size_t)s0 * F_OUT))[q];
        float4 v1 = ((const float4*)(xw + (size_t)s1 * F_OUT))[q];
        float4 v2 = ((const float4*)(xw + (size_t)s2 * F_OUT))[q];
        float4 v3 = ((const float4*)(xw + (size_t)s3 * F_OUT))[q];
        a0.x+=v0.x; a0.y+=v0.y; a0.z+=v0.z; a0.w+=v0.w;
        a1.x+=v1.x; a1.y+=v1.y; a1.z+=v1.z; a1.w+=v1.w;
        a2.x+=v2.x; a2.y+=v2.y; a2.z+=v2.z; a2.w+=v2.w;
        a3.x+=v3.x; a3.y+=v3.y; a3.z+=v3.z; a3.w+=v3.w;
    }
    for (; i + 8 <= cnt; i += 8) {
        int s0 = csr[start + i + eo];
        int s1 = csr[start + i + 4 + eo];
        float4 v0 = ((const float4*)(xw + (size_t)s0 * F_OUT))[q];
        float4 v1 = ((const float4*)(xw + (size_t)s1 * F_OUT))[q];
        a0.x+=v0.x; a0.y+=v0.y; a0.z+=v0.z; a0.w+=v0.w;
        a1.x+=v1.x; a1.y+=v1.y; a1.z+=v1.z; a1.w+=v1.w;
    }
    for (; i < cnt; i += 4) {
        if (i + eo < cnt) {
            int s0 = csr[start + i + eo];
            float4 v0 = ((const float4*)(xw + (size_t)s0 * F_OUT))[q];
            a0.x+=v0.x; a0.y+=v0.y; a0.z+=v0.z; a0.w+=v0.w;
        }
    }
    float4 acc;
    acc.x = a0.x+a1.x+a2.x+a3.x;
    acc.y = a0.y+a1.y+a2.y+a3.y;
    acc.z = a0.z+a1.z+a2.z+a3.z;
    acc.w = a0.w+a1.w+a2.w+a3.w;
    { float4 u = f4_shfl_xor(acc, 4); acc.x+=u.x; acc.y+=u.y; acc.z+=u.z; acc.w+=u.w; }
    { float4 u = f4_shfl_xor(acc, 8); acc.x+=u.x; acc.y+=u.y; acc.z+=u.z; acc.w+=u.w; }

    float4 sv = ((const float4*)(xw + (size_t)node * F_OUT))[q];
    float4 bq = ((const float4*)b1)[q];
    float4 h;
    h.x = fmaxf(dn * (acc.x + sv.x) + bq.x, 0.f);
    h.y = fmaxf(dn * (acc.y + sv.y) + bq.y, 0.f);
    h.z = fmaxf(dn * (acc.z + sv.z) + bq.z, 0.f);
    h.w = fmaxf(dn * (acc.w + sv.w) + bq.w, 0.f);

    // fused 16x16 GEMM: o_j = sum_r h[r] * W2[r][j], j = sub
    float o = 0.f;
#pragma unroll
    for (int a = 0; a < 4; a++) {
        int src = (grp << 4) + a;   // lane with q==a, eo==0 holds quarter a
        float h0 = __shfl(h.x, src);
        float h1 = __shfl(h.y, src);
        float h2 = __shfl(h.z, src);
        float h3 = __shfl(h.w, src);
        o += h0 * W2s[(a*4+0)*16 + sub] + h1 * W2s[(a*4+1)*16 + sub]
           + h2 * W2s[(a*4+2)*16 + sub] + h3 * W2s[(a*4+3)*16 + sub];
    }
    xw2p[(size_t)node * F_OUT + sub] = dn * o;
}

// ---------------- K7 v3: agg2 + bias + ReLU + fused mean-pool partials — 4-deep MLP ----------------
__global__ __launch_bounds__(256) void k_agg2(const float* __restrict__ xw, const int* __restrict__ offsets,
                                              const int* __restrict__ hist, const float* __restrict__ dinv,
                                              const int* __restrict__ csr, const float* __restrict__ b2,
                                              float* __restrict__ partials, int N) {
    int lane = threadIdx.x & 63;
    int wave = threadIdx.x >> 6;
    int grp  = lane >> 4;
    int sub  = lane & 15;
    int eo   = sub >> 2;
    int q    = sub & 3;
    int node = blockIdx.x * 16 + wave * 4 + grp;

    float4 m = make_float4(0.f, 0.f, 0.f, 0.f);
    if (node < N) {
        int start = offsets[node], cnt = hist[node];
        float dn = dinv[node];
        float4 a0 = make_float4(0.f,0.f,0.f,0.f), a1 = a0, a2 = a0, a3 = a0;
        int i = 0;
        for (; i + 16 <= cnt; i += 16) {
            int s0 = csr[start + i + eo];
            int s1 = csr[start + i + 4 + eo];
            int s2 = csr[start + i + 8 + eo];
            int s3 = csr[start + i + 12 + eo];
            float4 v0 = ((const float4*)(xw + (size_t)s0 * F_OUT))[q];
            float4 v1 = ((const float4*)(xw + (size_t)s1 * F_OUT))[q];
            float4 v2 = ((const float4*)(xw + (size_t)s2 * F_OUT))[q];
            float4 v3 = ((const float4*)(xw + (size_t)s3 * F_OUT))[q];
            a0.x+=v0.x; a0.y+=v0.y; a0.z+=v0.z; a0.w+=v0.w;
            a1.x+=v1.x; a1.y+=v1.y; a1.z+=v1.z; a1.w+=v1.w;
            a2.x+=v2.x; a2.y+=v2.y; a2.z+=v2.z; a2.w+=v2.w;
            a3.x+=v3.x; a3.y+=v3.y; a3.z+=v3.z; a3.w+=v3.w;
        }
        for (; i + 8 <= cnt; i += 8) {
            int s0 = csr[start + i + eo];
            int s1 = csr[start + i + 4 + eo];
            float4 v0 = ((const float4*)(xw + (size_t)s0 * F_OUT))[q];
            float4 v1 = ((const float4*)(xw + (size_t)s1 * F_OUT))[q];
            a0.x+=v0.x; a0.y+=v0.y; a0.z+=v0.z; a0.w+=v0.w;
            a1.x+=v1.x; a1.y+=v1.y; a1.z+=v1.z; a1.w+=v1.w;
        }
        for (; i < cnt; i += 4) {
            if (i + eo < cnt) {
                int s0 = csr[start + i + eo];
                float4 v0 = ((const float4*)(xw + (size_t)s0 * F_OUT))[q];
                a0.x+=v0.x; a0.y+=v0.y; a0.z+=v0.z; a0.w+=v0.w;
            }
        }
        float4 acc;
        acc.x = a0.x+a1.x+a2.x+a3.x;
        acc.y = a0.y+a1.y+a2.y+a3.y;
        acc.z = a0.z+a1.z+a2.z+a3.z;
        acc.w = a0.w+a1.w+a2.w+a3.w;
        { float4 u = f4_shfl_xor(acc, 4); acc.x+=u.x; acc.y+=u.y; acc.z+=u.z; acc.w+=u.w; }
        { float4 u = f4_shfl_xor(acc, 8); acc.x+=u.x; acc.y+=u.y; acc.z+=u.z; acc.w+=u.w; }
        float4 sv = ((const float4*)(xw + (size_t)node * F_OUT))[q];
        float4 bq = ((const float4*)b2)[q];
        if (eo == 0) {   // one copy per quarter for pooling
            m.x = fmaxf(dn * (acc.x + sv.x) + bq.x, 0.f);
            m.y = fmaxf(dn * (acc.y + sv.y) + bq.y, 0.f);
            m.z = fmaxf(dn * (acc.z + sv.z) + bq.z, 0.f);
            m.w = fmaxf(dn * (acc.w + sv.w) + bq.w, 0.f);
        }
    }
    // sum over the 4 groups (lane bits 4,5); eo!=0 lanes carry zeros
    { float4 u = f4_shfl_xor(m, 16); m.x+=u.x; m.y+=u.y; m.z+=u.z; m.w+=u.w; }
    { float4 u = f4_shfl_xor(m, 32); m.x+=u.x; m.y+=u.y; m.z+=u.z; m.w+=u.w; }
    __shared__ float smf[4][16];
    if (lane < 4) {   // lanes 0..3: eo=0, q=lane
        smf[wave][q*4+0] = m.x;
        smf[wave][q*4+1] = m.y;
        smf[wave][q*4+2] = m.z;
        smf[wave][q*4+3] = m.w;
    }
    __syncthreads();
    if (threadIdx.x < 16) {
        float s = smf[0][threadIdx.x] + smf[1][threadIdx.x] + smf[2][threadIdx.x] + smf[3][threadIdx.x];
        partials[(size_t)blockIdx.x * 16 + threadIdx.x] = s;
    }
}

// ---------------- K8: final reduce + fc ----------------
__global__ void k_final(const float* __restrict__ partials, int NB, const float* __restrict__ fc_w,
                        const float* __restrict__ fc_b, float* __restrict__ out, float invN) {
    __shared__ float sm[64][16];
    int t = threadIdx.x;  // 1024 threads
    int g = t >> 4, j = t & 15;
    float s = 0.0f;
    for (int bk = g; bk < NB; bk += 64) s += partials[(size_t)bk * 16 + j];
    sm[g][j] = s;
    __syncthreads();
    for (int str = 32; str > 0; str >>= 1) {
        if (g < str) sm[g][j] += sm[g + str][j];
        __syncthreads();
    }
    if (t == 0) {
        float acc = fc_b[0];
#pragma unroll
        for (int jj = 0; jj < 16; jj++) acc += sm[0][jj] * invN * fc_w[jj];
        out[0] = acc;
    }
}

extern "C" void kernel_launch(void* const* d_in, const int* in_sizes, int n_in,
                              void* d_out, int out_size, void* d_ws, size_t ws_size,
                              hipStream_t stream) {
    const float* x   = (const float*)d_in[0];
    const int*   ei  = (const int*)d_in[1];
    const float* W1  = (const float*)d_in[2];
    const float* b1  = (const float*)d_in[3];
    const float* W2  = (const float*)d_in[4];
    const float* b2  = (const float*)d_in[5];
    const float* fcw = (const float*)d_in[6];
    const float* fcb = (const float*)d_in[7];
    float* out = (float*)d_out;

    int N = in_sizes[0] / F_IN;            // 100000
    int E = in_sizes[1] / 2;               // 3200000
    int K1 = (N + CB_W - 1) >> CB_SHIFT;   // 391 coarse buckets
    int B1 = (E + PER - 1) / PER;          // 512 partition blocks

    // ---- workspace carve-up (256B aligned) ----
    char* p = (char*)d_ws;
    auto alloc = [&](size_t bytes) {
        void* r = (void*)p;
        p += (bytes + 255) & ~(size_t)255;
        return r;
    };
    int*   cntT       = (int*)alloc((size_t)K1 * B1 * 4);
    int*   baseT      = (int*)alloc((size_t)K1 * B1 * 4);
    int*   bucketBase = (int*)alloc((size_t)K1 * 4);
    int*   bucketCnt  = (int*)alloc((size_t)K1 * 4);
    int*   hist       = (int*)alloc((size_t)N * 4);
    int*   offsets    = (int*)alloc((size_t)N * 4);
    float* dinv       = (float*)alloc((size_t)N * 4);
    int*   csr        = (int*)alloc((size_t)E * 4);
    unsigned* part    = (unsigned*)alloc((size_t)E * 4);    // 12.8 MB
    int NB_NODE = (N + 15) / 16;                            // 6250
    float* partials = (float*)alloc((size_t)NB_NODE * 16 * 4);
    // alias: part region reused for xw after k_prep2 (2*N*16*4 == E*4)
    float* xw1p = (float*)part;
    float* xw2p = xw1p + (size_t)N * F_OUT;

    k_chist<<<B1, 256, 0, stream>>>(ei, E, K1, B1, cntT);
    k_btot<<<1, 512, 0, stream>>>(cntT, B1, K1, bucketBase, bucketCnt);
    k_bbase<<<K1, 512, 0, stream>>>(cntT, B1, bucketBase, baseT);
    k_csort<<<B1, 512, 0, stream>>>(ei, E, K1, B1, baseT, part);
    k_prep2<<<K1, 512, 0, stream>>>(part, bucketBase, bucketCnt, hist, dinv, offsets, csr, N);

    k_gemm1<<<(N + 255) / 256, 128, 0, stream>>>(x, W1, dinv, xw1p, N);
    k_agg1<<<NB_NODE, 256, 0, stream>>>(xw1p, offsets, hist, dinv, csr, b1, W2, xw2p, N);
    k_agg2<<<NB_NODE, 256, 0, stream>>>(xw2p, offsets, hist, dinv, csr, b2, partials, N);
    k_final<<<1, 1024, 0, stream>>>(partials, NB_NODE, fcw, fcb, out, 1.0f / (float)N);
}

// Round 9
// 237.034 us; speedup vs baseline: 3.5126x; 1.0910x over previous
//
#include <hip/hip_runtime.h>
#include <stdint.h>

#define F_IN 512
#define F_OUT 16
#define CB_SHIFT 8
#define CB_W 256          // nodes per coarse bucket
#define PER 6250          // edges per partition block (B1 = 512)
#define SORT_CAP 6400

__device__ inline float4 f4_shfl_xor(float4 v, int mask) {
    float4 r;
    r.x = __shfl_xor(v.x, mask);
    r.y = __shfl_xor(v.y, mask);
    r.z = __shfl_xor(v.z, mask);
    r.w = __shfl_xor(v.w, mask);
    return r;
}

// ---------------- P1: per-block LDS histogram over coarse buckets (TRANSPOSED out) ----------------
__global__ __launch_bounds__(256) void k_chist(const int* __restrict__ ei, int E, int K1, int B,
                                               int* __restrict__ cntT) {
    __shared__ int h[512];
    int t = threadIdx.x;
    for (int i = t; i < K1; i += 256) h[i] = 0;
    __syncthreads();
    int e0 = blockIdx.x * PER, e1 = min(E, e0 + PER);
    for (int e = e0 + t; e < e1; e += 256)
        atomicAdd(&h[ei[(size_t)E + e] >> CB_SHIFT], 1);
    __syncthreads();
    for (int i = t; i < K1; i += 256) cntT[(size_t)i * B + blockIdx.x] = h[i];
}

// ---------------- P2a: per-bucket totals + scan over K1 (single block) ----------------
__global__ __launch_bounds__(512) void k_btot(const int* __restrict__ cntT, int B, int K1,
                                              int* __restrict__ bucketBase, int* __restrict__ bucketCnt) {
    __shared__ int sm[512];
    int k = threadIdx.x;
    int tot = 0;
    if (k < K1) {
        const int4* row = (const int4*)(cntT + (size_t)k * B);
        for (int b = 0; b < B / 4; b++) {
            int4 v = row[b];
            tot += v.x + v.y + v.z + v.w;
        }
    }
    sm[k] = tot;
    __syncthreads();
    for (int off = 1; off < 512; off <<= 1) {
        int add = (k >= off) ? sm[k - off] : 0;
        __syncthreads();
        sm[k] += add;
        __syncthreads();
    }
    if (k < K1) { bucketBase[k] = sm[k] - tot; bucketCnt[k] = tot; }
}

// ---------------- P2b: per-(bucket,block) bases — coalesced scan per bucket ----------------
__global__ __launch_bounds__(512) void k_bbase(const int* __restrict__ cntT, int B,
                                               const int* __restrict__ bucketBase,
                                               int* __restrict__ baseT) {
    __shared__ int sm[512];
    int k = blockIdx.x, t = threadIdx.x;
    int v = (t < B) ? cntT[(size_t)k * B + t] : 0;
    sm[t] = v;
    __syncthreads();
    for (int off = 1; off < 512; off <<= 1) {
        int add = (t >= off) ? sm[t - off] : 0;
        __syncthreads();
        sm[t] += add;
        __syncthreads();
    }
    if (t < B) baseT[(size_t)k * B + t] = bucketBase[k] + sm[t] - v;  // exclusive
}

// ---------------- P3: per-block LDS counting sort, 16-lane-group copy-out ----------------
__global__ __launch_bounds__(512) void k_csort(const int* __restrict__ ei, int E, int K1, int B,
                                               const int* __restrict__ baseT, unsigned* __restrict__ part) {
    __shared__ unsigned sorted[SORT_CAP];
    __shared__ int h[512], lb[512], cur[512], gb[512];
    int t = threadIdx.x;
    int e0 = blockIdx.x * PER, e1 = min(E, e0 + PER);
    h[t] = 0;
    __syncthreads();
    for (int e = e0 + t; e < e1; e += 512)
        atomicAdd(&h[ei[(size_t)E + e] >> CB_SHIFT], 1);
    __syncthreads();
    int v = h[t];
    lb[t] = v;
    __syncthreads();
    for (int off = 1; off < 512; off <<= 1) {
        int add = (t >= off) ? lb[t - off] : 0;
        __syncthreads();
        lb[t] += add;
        __syncthreads();
    }
    int excl = lb[t] - v;
    __syncthreads();
    lb[t] = excl;
    cur[t] = excl;
    if (t < K1) gb[t] = baseT[(size_t)t * B + blockIdx.x];
    __syncthreads();
    for (int e = e0 + t; e < e1; e += 512) {
        int s = ei[e];
        int d = ei[(size_t)E + e];
        int pos = atomicAdd(&cur[d >> CB_SHIFT], 1);           // LDS atomic
        sorted[pos] = ((unsigned)s << CB_SHIFT) | (unsigned)(d & (CB_W - 1));
    }
    __syncthreads();
    // 16-lane group per bucket (runs avg ~16 elems): 32 bucket-groups per block
    int g16 = t >> 4, ln = t & 15;
    for (int k = g16; k < K1; k += 32) {
        int s0 = lb[k];
        int s1 = cur[k];          // after scatter, cur[k] == lb[k] + h[k]
        int g  = gb[k];
        for (int i = s0 + ln; i < s1; i += 16)
            part[(size_t)g + (i - s0)] = sorted[i];
    }
}

// ---------------- P4: per coarse bucket: node hist/dinv/offsets + CSR (512 threads) ----------------
__global__ __launch_bounds__(512) void k_prep2(const unsigned* __restrict__ part,
                                               const int* __restrict__ bucketBase, const int* __restrict__ bucketCnt,
                                               int* __restrict__ hist, float* __restrict__ dinv,
                                               int* __restrict__ offsets, int* __restrict__ csr, int N) {
    __shared__ int fh[CB_W], fb[CB_W], cur[CB_W];
    int k = blockIdx.x, t = threadIdx.x;
    int base = bucketBase[k], cnt = bucketCnt[k];
    int d0 = k << CB_SHIFT;
    if (t < CB_W) fh[t] = 0;
    __syncthreads();
    for (int i = t; i < cnt; i += 512)
        atomicAdd(&fh[part[(size_t)base + i] & (CB_W - 1)], 1);
    __syncthreads();
    int v = 0;
    if (t < CB_W) { v = fh[t]; fb[t] = v; }
    __syncthreads();
    for (int off = 1; off < CB_W; off <<= 1) {
        int add = (t >= off && t < CB_W) ? fb[t - off] : 0;
        __syncthreads();
        if (t < CB_W) fb[t] += add;
        __syncthreads();
    }
    if (t < CB_W) {
        int excl = fb[t] - v;
        int n = d0 + t;
        if (n < N) {
            offsets[n] = base + excl;
            hist[n] = v;
            dinv[n] = rsqrtf((float)(v + 1));
        }
        cur[t] = excl;
    }
    __syncthreads();
    for (int i = t; i < cnt; i += 512) {
        unsigned e = part[(size_t)base + i];
        int pos = atomicAdd(&cur[e & (CB_W - 1)], 1);
        csr[(size_t)base + pos] = (int)(e >> CB_SHIFT);
    }
}

// ---------------- K5 v5: xw1' = dinv[n] * (x @ W1) — SGPR W via uniform global reads, no LDS ----------------
__global__ __launch_bounds__(256) void k_gemm1(const float* __restrict__ x, const float* __restrict__ W1,
                                               const float* __restrict__ dinv, float* __restrict__ xw1p, int N) {
    int n = blockIdx.x * 256 + threadIdx.x;
    if (n >= N) return;
    const float4* xr = (const float4*)(x + (size_t)n * F_IN);
    const float4* wr = (const float4*)W1;   // thread-invariant address -> scalar (s_load) path

    float acc[16];
#pragma unroll
    for (int j = 0; j < 16; j++) acc[j] = 0.f;

#pragma unroll 4
    for (int kk = 0; kk < 128; kk++) {      // 4 k's per iter
        float4 xv = xr[kk];
#pragma unroll
        for (int i = 0; i < 4; i++) {
            float xs = (i == 0) ? xv.x : (i == 1) ? xv.y : (i == 2) ? xv.z : xv.w;
#pragma unroll
            for (int q = 0; q < 4; q++) {
                float4 wv = wr[kk * 16 + i * 4 + q];   // uniform -> SGPR
                acc[q*4+0] = fmaf(xs, wv.x, acc[q*4+0]);
                acc[q*4+1] = fmaf(xs, wv.y, acc[q*4+1]);
                acc[q*4+2] = fmaf(xs, wv.z, acc[q*4+2]);
                acc[q*4+3] = fmaf(xs, wv.w, acc[q*4+3]);
            }
        }
    }
    float dn = dinv[n];
    float4* orow = (float4*)(xw1p + (size_t)n * F_OUT);
#pragma unroll
    for (int q = 0; q < 4; q++)
        orow[q] = make_float4(dn*acc[q*4+0], dn*acc[q*4+1], dn*acc[q*4+2], dn*acc[q*4+3]);
}

// ---------------- K6 v4: agg1 + bias + ReLU + fused (h @ W2) * dinv — 8-deep gathers ----------------
// 16-lane group per node: lane = eo*4 + q (4 edge slots x 4 quarters)
__global__ __launch_bounds__(256) void k_agg1(const float* __restrict__ xw, const int* __restrict__ offsets,
                                              const int* __restrict__ hist, const float* __restrict__ dinv,
                                              const int* __restrict__ csr, const float* __restrict__ b1,
                                              const float* __restrict__ W2, float* __restrict__ xw2p, int N) {
    __shared__ float W2s[256];
    if (threadIdx.x < 256) W2s[threadIdx.x] = W2[threadIdx.x];
    __syncthreads();

    int lane = threadIdx.x & 63;
    int wave = threadIdx.x >> 6;
    int grp  = lane >> 4;
    int sub  = lane & 15;
    int eo   = sub >> 2;
    int q    = sub & 3;
    int node = blockIdx.x * 16 + wave * 4 + grp;
    if (node >= N) return;

    int start = offsets[node], cnt = hist[node];
    float dn = dinv[node];
    float4 a0 = make_float4(0.f,0.f,0.f,0.f), a1 = a0, a2 = a0, a3 = a0;
    int i = 0;
    for (; i + 32 <= cnt; i += 32) {
        int s0 = csr[start + i + eo];
        int s1 = csr[start + i + 4 + eo];
        int s2 = csr[start + i + 8 + eo];
        int s3 = csr[start + i + 12 + eo];
        int s4 = csr[start + i + 16 + eo];
        int s5 = csr[start + i + 20 + eo];
        int s6 = csr[start + i + 24 + eo];
        int s7 = csr[start + i + 28 + eo];
        float4 v0 = ((const float4*)(xw + (size_t)s0 * F_OUT))[q];
        float4 v1 = ((const float4*)(xw + (size_t)s1 * F_OUT))[q];
        float4 v2 = ((const float4*)(xw + (size_t)s2 * F_OUT))[q];
        float4 v3 = ((const float4*)(xw + (size_t)s3 * F_OUT))[q];
        float4 v4 = ((const float4*)(xw + (size_t)s4 * F_OUT))[q];
        float4 v5 = ((const float4*)(xw + (size_t)s5 * F_OUT))[q];
        float4 v6 = ((const float4*)(xw + (size_t)s6 * F_OUT))[q];
        float4 v7 = ((const float4*)(xw + (size_t)s7 * F_OUT))[q];
        a0.x+=v0.x; a0.y+=v0.y; a0.z+=v0.z; a0.w+=v0.w;
        a1.x+=v1.x; a1.y+=v1.y; a1.z+=v1.z; a1.w+=v1.w;
        a2.x+=v2.x; a2.y+=v2.y; a2.z+=v2.z; a2.w+=v2.w;
        a3.x+=v3.x; a3.y+=v3.y; a3.z+=v3.z; a3.w+=v3.w;
        a0.x+=v4.x; a0.y+=v4.y; a0.z+=v4.z; a0.w+=v4.w;
        a1.x+=v5.x; a1.y+=v5.y; a1.z+=v5.z; a1.w+=v5.w;
        a2.x+=v6.x; a2.y+=v6.y; a2.z+=v6.z; a2.w+=v6.w;
        a3.x+=v7.x; a3.y+=v7.y; a3.z+=v7.z; a3.w+=v7.w;
    }
    for (; i + 16 <= cnt; i += 16) {
        int s0 = csr[start + i + eo];
        int s1 = csr[start + i + 4 + eo];
        int s2 = csr[start + i + 8 + eo];
        int s3 = csr[start + i + 12 + eo];
        float4 v0 = ((const float4*)(xw + (size_t)s0 * F_OUT))[q];
        float4 v1 = ((const float4*)(xw + (size_t)s1 * F_OUT))[q];
        float4 v2 = ((const float4*)(xw + (size_t)s2 * F_OUT))[q];
        float4 v3 = ((const float4*)(xw + (size_t)s3 * F_OUT))[q];
        a0.x+=v0.x; a0.y+=v0.y; a0.z+=v0.z; a0.w+=v0.w;
        a1.x+=v1.x; a1.y+=v1.y; a1.z+=v1.z; a1.w+=v1.w;
        a2.x+=v2.x; a2.y+=v2.y; a2.z+=v2.z; a2.w+=v2.w;
        a3.x+=v3.x; a3.y+=v3.y; a3.z+=v3.z; a3.w+=v3.w;
    }
    for (; i + 8 <= cnt; i += 8) {
        int s0 = csr[start + i + eo];
        int s1 = csr[start + i + 4 + eo];
        float4 v0 = ((const float4*)(xw + (size_t)s0 * F_OUT))[q];
        float4 v1 = ((const float4*)(xw + (size_t)s1 * F_OUT))[q];
        a0.x+=v0.x; a0.y+=v0.y; a0.z+=v0.z; a0.w+=v0.w;
        a1.x+=v1.x; a1.y+=v1.y; a1.z+=v1.z; a1.w+=v1.w;
    }
    for (; i < cnt; i += 4) {
        if (i + eo < cnt) {
            int s0 = csr[start + i + eo];
            float4 v0 = ((const float4*)(xw + (size_t)s0 * F_OUT))[q];
            a0.x+=v0.x; a0.y+=v0.y; a0.z+=v0.z; a0.w+=v0.w;
        }
    }
    float4 acc;
    acc.x = a0.x+a1.x+a2.x+a3.x;
    acc.y = a0.y+a1.y+a2.y+a3.y;
    acc.z = a0.z+a1.z+a2.z+a3.z;
    acc.w = a0.w+a1.w+a2.w+a3.w;
    { float4 u = f4_shfl_xor(acc, 4); acc.x+=u.x; acc.y+=u.y; acc.z+=u.z; acc.w+=u.w; }
    { float4 u = f4_shfl_xor(acc, 8); acc.x+=u.x; acc.y+=u.y; acc.z+=u.z; acc.w+=u.w; }

    float4 sv = ((const float4*)(xw + (size_t)node * F_OUT))[q];
    float4 bq = ((const float4*)b1)[q];
    float4 h;
    h.x = fmaxf(dn * (acc.x + sv.x) + bq.x, 0.f);
    h.y = fmaxf(dn * (acc.y + sv.y) + bq.y, 0.f);
    h.z = fmaxf(dn * (acc.z + sv.z) + bq.z, 0.f);
    h.w = fmaxf(dn * (acc.w + sv.w) + bq.w, 0.f);

    // fused 16x16 GEMM: o_j = sum_r h[r] * W2[r][j], j = sub
    float o = 0.f;
#pragma unroll
    for (int a = 0; a < 4; a++) {
        int src = (grp << 4) + a;   // lane with q==a, eo==0 holds quarter a
        float h0 = __shfl(h.x, src);
        float h1 = __shfl(h.y, src);
        float h2 = __shfl(h.z, src);
        float h3 = __shfl(h.w, src);
        o += h0 * W2s[(a*4+0)*16 + sub] + h1 * W2s[(a*4+1)*16 + sub]
           + h2 * W2s[(a*4+2)*16 + sub] + h3 * W2s[(a*4+3)*16 + sub];
    }
    xw2p[(size_t)node * F_OUT + sub] = dn * o;
}

// ---------------- K7 v4: agg2 + bias + ReLU + fused mean-pool partials — 8-deep gathers ----------------
__global__ __launch_bounds__(256) void k_agg2(const float* __restrict__ xw, const int* __restrict__ offsets,
                                              const int* __restrict__ hist, const float* __restrict__ dinv,
                                              const int* __restrict__ csr, const float* __restrict__ b2,
                                              float* __restrict__ partials, int N) {
    int lane = threadIdx.x & 63;
    int wave = threadIdx.x >> 6;
    int grp  = lane >> 4;
    int sub  = lane & 15;
    int eo   = sub >> 2;
    int q    = sub & 3;
    int node = blockIdx.x * 16 + wave * 4 + grp;

    float4 m = make_float4(0.f, 0.f, 0.f, 0.f);
    if (node < N) {
        int start = offsets[node], cnt = hist[node];
        float dn = dinv[node];
        float4 a0 = make_float4(0.f,0.f,0.f,0.f), a1 = a0, a2 = a0, a3 = a0;
        int i = 0;
        for (; i + 32 <= cnt; i += 32) {
            int s0 = csr[start + i + eo];
            int s1 = csr[start + i + 4 + eo];
            int s2 = csr[start + i + 8 + eo];
            int s3 = csr[start + i + 12 + eo];
            int s4 = csr[start + i + 16 + eo];
            int s5 = csr[start + i + 20 + eo];
            int s6 = csr[start + i + 24 + eo];
            int s7 = csr[start + i + 28 + eo];
            float4 v0 = ((const float4*)(xw + (size_t)s0 * F_OUT))[q];
            float4 v1 = ((const float4*)(xw + (size_t)s1 * F_OUT))[q];
            float4 v2 = ((const float4*)(xw + (size_t)s2 * F_OUT))[q];
            float4 v3 = ((const float4*)(xw + (size_t)s3 * F_OUT))[q];
            float4 v4 = ((const float4*)(xw + (size_t)s4 * F_OUT))[q];
            float4 v5 = ((const float4*)(xw + (size_t)s5 * F_OUT))[q];
            float4 v6 = ((const float4*)(xw + (size_t)s6 * F_OUT))[q];
            float4 v7 = ((const float4*)(xw + (size_t)s7 * F_OUT))[q];
            a0.x+=v0.x; a0.y+=v0.y; a0.z+=v0.z; a0.w+=v0.w;
            a1.x+=v1.x; a1.y+=v1.y; a1.z+=v1.z; a1.w+=v1.w;
            a2.x+=v2.x; a2.y+=v2.y; a2.z+=v2.z; a2.w+=v2.w;
            a3.x+=v3.x; a3.y+=v3.y; a3.z+=v3.z; a3.w+=v3.w;
            a0.x+=v4.x; a0.y+=v4.y; a0.z+=v4.z; a0.w+=v4.w;
            a1.x+=v5.x; a1.y+=v5.y; a1.z+=v5.z; a1.w+=v5.w;
            a2.x+=v6.x; a2.y+=v6.y; a2.z+=v6.z; a2.w+=v6.w;
            a3.x+=v7.x; a3.y+=v7.y; a3.z+=v7.z; a3.w+=v7.w;
        }
        for (; i + 16 <= cnt; i += 16) {
            int s0 = csr[start + i + eo];
            int s1 = csr[start + i + 4 + eo];
            int s2 = csr[start + i + 8 + eo];
            int s3 = csr[start + i + 12 + eo];
            float4 v0 = ((const float4*)(xw + (size_t)s0 * F_OUT))[q];
            float4 v1 = ((const float4*)(xw + (size_t)s1 * F_OUT))[q];
            float4 v2 = ((const float4*)(xw + (size_t)s2 * F_OUT))[q];
            float4 v3 = ((const float4*)(xw + (size_t)s3 * F_OUT))[q];
            a0.x+=v0.x; a0.y+=v0.y; a0.z+=v0.z; a0.w+=v0.w;
            a1.x+=v1.x; a1.y+=v1.y; a1.z+=v1.z; a1.w+=v1.w;
            a2.x+=v2.x; a2.y+=v2.y; a2.z+=v2.z; a2.w+=v2.w;
            a3.x+=v3.x; a3.y+=v3.y; a3.z+=v3.z; a3.w+=v3.w;
        }
        for (; i + 8 <= cnt; i += 8) {
            int s0 = csr[start + i + eo];
            int s1 = csr[start + i + 4 + eo];
            float4 v0 = ((const float4*)(xw + (size_t)s0 * F_OUT))[q];
            float4 v1 = ((const float4*)(xw + (size_t)s1 * F_OUT))[q];
            a0.x+=v0.x; a0.y+=v0.y; a0.z+=v0.z; a0.w+=v0.w;
            a1.x+=v1.x; a1.y+=v1.y; a1.z+=v1.z; a1.w+=v1.w;
        }
        for (; i < cnt; i += 4) {
            if (i + eo < cnt) {
                int s0 = csr[start + i + eo];
                float4 v0 = ((const float4*)(xw + (size_t)s0 * F_OUT))[q];
                a0.x+=v0.x; a0.y+=v0.y; a0.z+=v0.z; a0.w+=v0.w;
            }
        }
        float4 acc;
        acc.x = a0.x+a1.x+a2.x+a3.x;
        acc.y = a0.y+a1.y+a2.y+a3.y;
        acc.z = a0.z+a1.z+a2.z+a3.z;
        acc.w = a0.w+a1.w+a2.w+a3.w;
        { float4 u = f4_shfl_xor(acc, 4); acc.x+=u.x; acc.y+=u.y; acc.z+=u.z; acc.w+=u.w; }
        { float4 u = f4_shfl_xor(acc, 8); acc.x+=u.x; acc.y+=u.y; acc.z+=u.z; acc.w+=u.w; }
        float4 sv = ((const float4*)(xw + (size_t)node * F_OUT))[q];
        float4 bq = ((const float4*)b2)[q];
        if (eo == 0) {   // one copy per quarter for pooling
            m.x = fmaxf(dn * (acc.x + sv.x) + bq.x, 0.f);
            m.y = fmaxf(dn * (acc.y + sv.y) + bq.y, 0.f);
            m.z = fmaxf(dn * (acc.z + sv.z) + bq.z, 0.f);
            m.w = fmaxf(dn * (acc.w + sv.w) + bq.w, 0.f);
        }
    }
    // sum over the 4 groups (lane bits 4,5); eo!=0 lanes carry zeros
    { float4 u = f4_shfl_xor(m, 16); m.x+=u.x; m.y+=u.y; m.z+=u.z; m.w+=u.w; }
    { float4 u = f4_shfl_xor(m, 32); m.x+=u.x; m.y+=u.y; m.z+=u.z; m.w+=u.w; }
    __shared__ float smf[4][16];
    if (lane < 4) {   // lanes 0..3: eo=0, q=lane
        smf[wave][q*4+0] = m.x;
        smf[wave][q*4+1] = m.y;
        smf[wave][q*4+2] = m.z;
        smf[wave][q*4+3] = m.w;
    }
    __syncthreads();
    if (threadIdx.x < 16) {
        float s = smf[0][threadIdx.x] + smf[1][threadIdx.x] + smf[2][threadIdx.x] + smf[3][threadIdx.x];
        partials[(size_t)blockIdx.x * 16 + threadIdx.x] = s;
    }
}

// ---------------- K8: final reduce + fc ----------------
__global__ void k_final(const float* __restrict__ partials, int NB, const float* __restrict__ fc_w,
                        const float* __restrict__ fc_b, float* __restrict__ out, float invN) {
    __shared__ float sm[64][16];
    int t = threadIdx.x;  // 1024 threads
    int g = t >> 4, j = t & 15;
    float s = 0.0f;
    for (int bk = g; bk < NB; bk += 64) s += partials[(size_t)bk * 16 + j];
    sm[g][j] = s;
    __syncthreads();
    for (int str = 32; str > 0; str >>= 1) {
        if (g < str) sm[g][j] += sm[g + str][j];
        __syncthreads();
    }
    if (t == 0) {
        float acc = fc_b[0];
#pragma unroll
        for (int jj = 0; jj < 16; jj++) acc += sm[0][jj] * invN * fc_w[jj];
        out[0] = acc;
    }
}

extern "C" void kernel_launch(void* const* d_in, const int* in_sizes, int n_in,
                              void* d_out, int out_size, void* d_ws, size_t ws_size,
                              hipStream_t stream) {
    const float* x   = (const float*)d_in[0];
    const int*   ei  = (const int*)d_in[1];
    const float* W1  = (const float*)d_in[2];
    const float* b1  = (const float*)d_in[3];
    const float* W2  = (const float*)d_in[4];
    const float* b2  = (const float*)d_in[5];
    const float* fcw = (const float*)d_in[6];
    const float* fcb = (const float*)d_in[7];
    float* out = (float*)d_out;

    int N = in_sizes[0] / F_IN;            // 100000
    int E = in_sizes[1] / 2;               // 3200000
    int K1 = (N + CB_W - 1) >> CB_SHIFT;   // 391 coarse buckets
    int B1 = (E + PER - 1) / PER;          // 512 partition blocks

    // ---- workspace carve-up (256B aligned) ----
    char* p = (char*)d_ws;
    auto alloc = [&](size_t bytes) {
        void* r = (void*)p;
        p += (bytes + 255) & ~(size_t)255;
        return r;
    };
    int*   cntT       = (int*)alloc((size_t)K1 * B1 * 4);
    int*   baseT      = (int*)alloc((size_t)K1 * B1 * 4);
    int*   bucketBase = (int*)alloc((size_t)K1 * 4);
    int*   bucketCnt  = (int*)alloc((size_t)K1 * 4);
    int*   hist       = (int*)alloc((size_t)N * 4);
    int*   offsets    = (int*)alloc((size_t)N * 4);
    float* dinv       = (float*)alloc((size_t)N * 4);
    int*   csr        = (int*)alloc((size_t)E * 4);
    unsigned* part    = (unsigned*)alloc((size_t)E * 4);    // 12.8 MB
    int NB_NODE = (N + 15) / 16;                            // 6250
    float* partials = (float*)alloc((size_t)NB_NODE * 16 * 4);
    // alias: part region reused for xw after k_prep2 (2*N*16*4 == E*4)
    float* xw1p = (float*)part;
    float* xw2p = xw1p + (size_t)N * F_OUT;

    k_chist<<<B1, 256, 0, stream>>>(ei, E, K1, B1, cntT);
    k_btot<<<1, 512, 0, stream>>>(cntT, B1, K1, bucketBase, bucketCnt);
    k_bbase<<<K1, 512, 0, stream>>>(cntT, B1, bucketBase, baseT);
    k_csort<<<B1, 512, 0, stream>>>(ei, E, K1, B1, baseT, part);
    k_prep2<<<K1, 512, 0, stream>>>(part, bucketBase, bucketCnt, hist, dinv, offsets, csr, N);

    k_gemm1<<<(N + 255) / 256, 256, 0, stream>>>(x, W1, dinv, xw1p, N);
    k_agg1<<<NB_NODE, 256, 0, stream>>>(xw1p, offsets, hist, dinv, csr, b1, W2, xw2p, N);
    k_agg2<<<NB_NODE, 256, 0, stream>>>(xw2p, offsets, hist, dinv, csr, b2, partials, N);
    k_final<<<1, 1024, 0, stream>>>(partials, NB_NODE, fcw, fcb, out, 1.0f / (float)N);
}